// Round 13
// baseline (141.109 us; speedup 1.0000x reference)
//
#include <hip/hip_runtime.h>
#include <hip/hip_fp16.h>

#define HDIM 16
#define FIN 54
#define BSHIFT 7                  // 128 nodes per bucket
#define BNODES (1 << BSHIFT)      // 128
#define NB_BLK 256                // binning blocks == histogram columns
#define FBT 1024                  // threads in hist/fill blocks
#define LST 512                   // threads in local_sort blocks
#define CAP 6144                  // LDS stage entries in local_sort (24 KB)
#define GTILE 256                 // rows per gemm block
#define GPAD 55                   // padded row stride in LDS (gcd(55,32)=1)
#define SENTINEL 0xFFFFFFFFu

// ---------------------------------------------------------------------------
// pass A1: per-(bucket,block) histogram of dst>>7 (bucket-major) + per-bucket
// totals (btot, pre-zeroed). gh[M] = 0 so the padded scan yields gh[M]=total.
// ---------------------------------------------------------------------------
__global__ __launch_bounds__(FBT)
void hist_kernel(const int* __restrict__ dst, int* __restrict__ gh,
                 int* __restrict__ btot, int E, int nb, int M) {
    __shared__ int lh[800];                 // nb = 782 <= 800
    for (int t = threadIdx.x; t < nb; t += FBT) lh[t] = 0;
    __syncthreads();
    int per = (((E + NB_BLK - 1) / NB_BLK) + 3) & ~3;
    int s0 = blockIdx.x * per;              // multiple of 4
    int s1 = min(E, s0 + per);
    int idx = s0 + (threadIdx.x << 2);
    for (; idx + 3 < s1; idx += (FBT << 2)) {
        int4 d4 = *(const int4*)&dst[idx];
        atomicAdd(&lh[d4.x >> BSHIFT], 1);
        atomicAdd(&lh[d4.y >> BSHIFT], 1);
        atomicAdd(&lh[d4.z >> BSHIFT], 1);
        atomicAdd(&lh[d4.w >> BSHIFT], 1);
    }
    if (idx < s1) {
        int stop = min(idx + 4, s1);
        for (int e = idx; e < stop; ++e) atomicAdd(&lh[dst[e] >> BSHIFT], 1);
    }
    __syncthreads();
    for (int t = threadIdx.x; t < nb; t += FBT) {
        int v = lh[t];
        gh[t * NB_BLK + blockIdx.x] = v;
        if (v) atomicAdd(&btot[t], v);
    }
    if (blockIdx.x == 0 && threadIdx.x == 0) gh[M] = 0;
}

// ---------------------------------------------------------------------------
// exclusive scan of PADDED counts ((v+15)&~15), in place over M+1 elems
// ---------------------------------------------------------------------------
__global__ void scan1_kernel(int* __restrict__ data, int* __restrict__ bsum, int n) {
    __shared__ int sh[256];
    int off = blockIdx.x * 4096 + threadIdx.x * 16;
    int vals[16];
    int local = 0;
#pragma unroll
    for (int k = 0; k < 16; ++k) {
        int v = (off + k < n) ? ((data[off + k] + 15) & ~15) : 0;
        vals[k] = v;
        local += v;
    }
    sh[threadIdx.x] = local;
    __syncthreads();
#pragma unroll
    for (int d = 1; d < 256; d <<= 1) {
        int t = (threadIdx.x >= d) ? sh[threadIdx.x - d] : 0;
        __syncthreads();
        sh[threadIdx.x] += t;
        __syncthreads();
    }
    int run = (threadIdx.x == 0) ? 0 : sh[threadIdx.x - 1];
#pragma unroll
    for (int k = 0; k < 16; ++k) {
        if (off + k < n) data[off + k] = run;
        run += vals[k];
    }
    if (threadIdx.x == 0) bsum[blockIdx.x] = sh[255];
}

__global__ void scan2_kernel(int* __restrict__ bsum, int nb) {
    __shared__ int sh[512];
    int v = (threadIdx.x < nb) ? bsum[threadIdx.x] : 0;
    sh[threadIdx.x] = v;
    __syncthreads();
    for (int d = 1; d < 512; d <<= 1) {
        int t = (threadIdx.x >= d) ? sh[threadIdx.x - d] : 0;
        __syncthreads();
        sh[threadIdx.x] += t;
        __syncthreads();
    }
    int excl = (threadIdx.x == 0) ? 0 : sh[threadIdx.x - 1];
    if (threadIdx.x < nb) bsum[threadIdx.x] = excl;
}

// finalize (M+1 elems) + segstart extraction: segstart[i/256] = gh[i] at i%256==0
// (i == M lands on segstart[nb] = padded total, since M % 256 == 0)
__global__ void scan3_kernel(int* __restrict__ data, const int* __restrict__ bsum,
                             int* __restrict__ segstart, int ntot) {
    int i = blockIdx.x * blockDim.x + threadIdx.x;
    if (i < ntot) {
        int v = data[i] + bsum[i >> 12];
        data[i] = v;
        if ((i & (NB_BLK - 1)) == 0) segstart[i / NB_BLK] = v;
    }
}

// compact bucket starts: c0 = exclusive scan of btot; c0[nb] = E
__global__ void scanb_kernel(const int* __restrict__ btot, int* __restrict__ c0,
                             int nb, int E) {
    __shared__ int sh[1024];
    int t = threadIdx.x;
    sh[t] = (t < nb) ? btot[t] : 0;
    __syncthreads();
    for (int d = 1; d < 1024; d <<= 1) {
        int v = (t >= d) ? sh[t - d] : 0;
        __syncthreads();
        sh[t] += v;
        __syncthreads();
    }
    if (t < nb) c0[t] = (t == 0) ? 0 : sh[t - 1];
    if (t == nb) c0[t] = E;
}

// ---------------------------------------------------------------------------
// pass A2: place edges into 64B-ALIGNED per-(bucket,block) cells; pad tails
// get SENTINEL. Each 64B line is written by exactly one block.
// ---------------------------------------------------------------------------
__global__ __launch_bounds__(FBT)
void fill_binned_kernel(const int* __restrict__ src, const int* __restrict__ dst,
                        const int* __restrict__ gh,
                        unsigned int* __restrict__ binned, int E, int nb) {
    __shared__ int lcur[800];
    for (int t = threadIdx.x; t < nb; t += FBT)
        lcur[t] = gh[t * NB_BLK + blockIdx.x];
    __syncthreads();
    int per = (((E + NB_BLK - 1) / NB_BLK) + 3) & ~3;
    int s0 = blockIdx.x * per;
    int s1 = min(E, s0 + per);
    int idx = s0 + (threadIdx.x << 2);
    for (; idx + 3 < s1; idx += (FBT << 2)) {
        int4 d4 = *(const int4*)&dst[idx];
        int4 v4 = *(const int4*)&src[idx];
        int p0 = atomicAdd(&lcur[d4.x >> BSHIFT], 1);
        int p1 = atomicAdd(&lcur[d4.y >> BSHIFT], 1);
        int p2 = atomicAdd(&lcur[d4.z >> BSHIFT], 1);
        int p3 = atomicAdd(&lcur[d4.w >> BSHIFT], 1);
        binned[p0] = ((unsigned int)v4.x << BSHIFT) | (unsigned int)(d4.x & (BNODES - 1));
        binned[p1] = ((unsigned int)v4.y << BSHIFT) | (unsigned int)(d4.y & (BNODES - 1));
        binned[p2] = ((unsigned int)v4.z << BSHIFT) | (unsigned int)(d4.z & (BNODES - 1));
        binned[p3] = ((unsigned int)v4.w << BSHIFT) | (unsigned int)(d4.w & (BNODES - 1));
    }
    if (idx < s1) {
        int stop = min(idx + 4, s1);
        for (int e = idx; e < stop; ++e) {
            int d = dst[e];
            int pos = atomicAdd(&lcur[d >> BSHIFT], 1);
            binned[pos] = ((unsigned int)src[e] << BSHIFT) | (unsigned int)(d & (BNODES - 1));
        }
    }
    __syncthreads();
    // sentinel pad tails: cell (t, blk) occupies [gh[i], gh[i+1]), i = t*NB_BLK+blk
    for (int t = threadIdx.x; t < nb; t += FBT) {
        int endp = gh[t * NB_BLK + blockIdx.x + 1];
        for (int k = lcur[t]; k < endp; ++k) binned[k] = SENTINEL;
    }
}

// ---------------------------------------------------------------------------
// pass B: per-bucket counting sort (skip sentinels) -> compact col/cs + dinv
// ---------------------------------------------------------------------------
__global__ __launch_bounds__(LST)
void local_sort_kernel(const unsigned int* __restrict__ binned,
                       const int* __restrict__ segstart, const int* __restrict__ c0,
                       unsigned int* __restrict__ col, int* __restrict__ cs,
                       float* __restrict__ dinv, int n) {
    __shared__ unsigned int stage[CAP];     // 24 KB
    __shared__ int hist[BNODES], scn[BNODES], cur[BNODES];
    int b = blockIdx.x;
    int s0 = segstart[b], s1 = segstart[b + 1];   // padded binned segment
    int c0b = c0[b];                               // compact col start
    int t = threadIdx.x;

    if (t < BNODES) hist[t] = 0;
    __syncthreads();
    for (int k = s0 + t; k < s1; k += LST) {
        unsigned int p = binned[k];
        if (p != SENTINEL) atomicAdd(&hist[p & (BNODES - 1)], 1);
    }
    __syncthreads();
    if (t < BNODES) scn[t] = hist[t];
    __syncthreads();
    for (int d = 1; d < BNODES; d <<= 1) {
        int v = (t < BNODES && t >= d) ? scn[t - d] : 0;
        __syncthreads();
        if (t < BNODES) scn[t] += v;
        __syncthreads();
    }
    if (t < BNODES) {
        int excl = scn[t] - hist[t];        // exclusive scan
        cur[t] = excl;
        int node = (b << BSHIFT) + t;
        if (node < n) {
            cs[node] = c0b + excl;
            dinv[node] = rsqrtf((float)hist[t] + 1.0f);
        }
    }
    __syncthreads();
    for (int k = s0 + t; k < s1; k += LST) {
        unsigned int p = binned[k];
        if (p == SENTINEL) continue;
        int pos = atomicAdd(&cur[p & (BNODES - 1)], 1);
        unsigned int sv = p >> BSHIFT;
        if (pos < CAP) stage[pos] = sv;
        else col[c0b + pos] = sv;           // statistically-never overflow path
    }
    __syncthreads();
    int len = scn[BNODES - 1];              // real entries in bucket
    if (len > CAP) len = CAP;
    for (int k = t; k < len; k += LST) col[c0b + k] = stage[k];   // coalesced
}

// ---------------------------------------------------------------------------
// hA[row,:] = fp16( dinv[row] * (x[row,:] @ W1) ), x staged in LDS coalesced
// ---------------------------------------------------------------------------
__global__ __launch_bounds__(256)
void gemm_kernel(const float* __restrict__ X, const float* __restrict__ W,
                 const float* __restrict__ dinv, __half* __restrict__ Yh, int n) {
    __shared__ float Wl[FIN * HDIM];       // 3456 B
    __shared__ float xl[GTILE * GPAD];     // 56320 B
    for (int t = threadIdx.x; t < FIN * HDIM; t += blockDim.x) Wl[t] = W[t];

    int base = blockIdx.x * GTILE;
    int nrows = min(GTILE, n - base);
    const float* xb = X + (size_t)base * FIN;
    int tot = nrows * FIN;
    for (int i4 = threadIdx.x; i4 < (tot >> 2); i4 += blockDim.x) {
        float4 v = ((const float4*)xb)[i4];
        int i = i4 << 2;
        int r = i / FIN;
        int c = i - r * FIN;
#pragma unroll
        for (int u = 0; u < 4; ++u) {
            int cc = c + u, rr = r;
            if (cc >= FIN) { cc -= FIN; ++rr; }
            xl[rr * GPAD + cc] = (&v.x)[u];
        }
    }
    for (int i = (tot & ~3) + threadIdx.x; i < tot; i += blockDim.x) {
        int r = i / FIN;
        xl[r * GPAD + (i - r * FIN)] = xb[i];
    }
    __syncthreads();

    int t = threadIdx.x;
    if (t < nrows) {
        int row = base + t;
        const float* xr = &xl[t * GPAD];
        float acc[HDIM];
#pragma unroll
        for (int j = 0; j < HDIM; ++j) acc[j] = 0.0f;
#pragma unroll
        for (int k = 0; k < FIN; ++k) {
            float xv = xr[k];
#pragma unroll
            for (int j = 0; j < HDIM; ++j)
                acc[j] = fmaf(xv, Wl[k * HDIM + j], acc[j]);
        }
        float di = dinv[row];
        __half2 hh[8];
#pragma unroll
        for (int j = 0; j < 8; ++j)
            hh[j] = __floats2half2_rn(di * acc[2 * j], di * acc[2 * j + 1]);
        uint4* yo = (uint4*)(Yh + ((size_t)row << 4));
        yo[0] = *(uint4*)&hh[0];
        yo[1] = *(uint4*)&hh[4];
    }
}

// ---------------------------------------------------------------------------
// Gather: 4 lanes per node; hs in fp16 (32 B/node -> 3.2 MB, L2-resident).
// ---------------------------------------------------------------------------
__device__ __forceinline__ float4 ld_h4(const __half* __restrict__ hsh,
                                        unsigned int node, int q) {
    const __half2* p = (const __half2*)(hsh + ((size_t)node << 4) + (q << 2));
    float2 fa = __half22float2(p[0]);
    float2 fb = __half22float2(p[1]);
    return make_float4(fa.x, fa.y, fb.x, fb.y);
}

template <bool FUSE_W2>
__global__ void gather_kernel(const unsigned int* __restrict__ col, const int* __restrict__ cs,
                              const __half* __restrict__ hsh, const float* __restrict__ dinv,
                              const float* __restrict__ bias, const float* __restrict__ W2,
                              __half* __restrict__ outh, float4* __restrict__ out4,
                              int n, int E) {
    __shared__ float4 W2l[HDIM * 4];   // W2l[jj*4+q] = W2[jj][4q..4q+3]
    if constexpr (FUSE_W2) {
        for (int t = threadIdx.x; t < HDIM * 4; t += blockDim.x)
            W2l[t] = ((const float4*)W2)[t];
        __syncthreads();
    }
    int idx = blockIdx.x * blockDim.x + threadIdx.x;
    int i = idx >> 2;
    int q = idx & 3;
    if (i >= n) return;
    int start = cs[i];
    int end = (i + 1 < n) ? cs[i + 1] : E;

    float4 acc = ld_h4(hsh, (unsigned int)i, q);   // self-loop term
    int k = start;
    for (; k + 7 < end; k += 8) {
        unsigned int s[8];
#pragma unroll
        for (int u = 0; u < 8; ++u) s[u] = col[k + u];
        float4 h[8];
#pragma unroll
        for (int u = 0; u < 8; ++u) h[u] = ld_h4(hsh, s[u], q);
#pragma unroll
        for (int u = 0; u < 8; ++u) {
            acc.x += h[u].x; acc.y += h[u].y; acc.z += h[u].z; acc.w += h[u].w;
        }
    }
    for (; k < end; ++k) {
        float4 h = ld_h4(hsh, col[k], q);
        acc.x += h.x; acc.y += h.y; acc.z += h.z; acc.w += h.w;
    }

    float di = dinv[i];
    float4 b4 = ((const float4*)bias)[q];
    float4 r;
    r.x = fmaxf(fmaf(di, acc.x, b4.x), 0.0f);
    r.y = fmaxf(fmaf(di, acc.y, b4.y), 0.0f);
    r.z = fmaxf(fmaf(di, acc.z, b4.z), 0.0f);
    r.w = fmaxf(fmaf(di, acc.w, b4.w), 0.0f);

    if constexpr (FUSE_W2) {
        int lane = threadIdx.x & 63;
        int base = lane & ~3;
        float4 o = make_float4(0.f, 0.f, 0.f, 0.f);
#pragma unroll
        for (int p = 0; p < 4; ++p) {
            float rx = __shfl(r.x, base + p, 64);
            float ry = __shfl(r.y, base + p, 64);
            float rz = __shfl(r.z, base + p, 64);
            float rw = __shfl(r.w, base + p, 64);
            float4 w0 = W2l[(p * 4 + 0) * 4 + q];
            float4 w1 = W2l[(p * 4 + 1) * 4 + q];
            float4 w2 = W2l[(p * 4 + 2) * 4 + q];
            float4 w3 = W2l[(p * 4 + 3) * 4 + q];
            o.x = fmaf(rx, w0.x, fmaf(ry, w1.x, fmaf(rz, w2.x, fmaf(rw, w3.x, o.x))));
            o.y = fmaf(rx, w0.y, fmaf(ry, w1.y, fmaf(rz, w2.y, fmaf(rw, w3.y, o.y))));
            o.z = fmaf(rx, w0.z, fmaf(ry, w1.z, fmaf(rz, w2.z, fmaf(rw, w3.z, o.z))));
            o.w = fmaf(rx, w0.w, fmaf(ry, w1.w, fmaf(rz, w2.w, fmaf(rw, w3.w, o.w))));
        }
        __half2 o01 = __floats2half2_rn(di * o.x, di * o.y);
        __half2 o23 = __floats2half2_rn(di * o.z, di * o.w);
        uint2 pk;
        pk.x = *(unsigned int*)&o01;
        pk.y = *(unsigned int*)&o23;
        *(uint2*)(outh + ((size_t)i << 4) + (q << 2)) = pk;
    } else {
        out4[(size_t)i * 4 + q] = r;
    }
}

extern "C" void kernel_launch(void* const* d_in, const int* in_sizes, int n_in,
                              void* d_out, int out_size, void* d_ws, size_t ws_size,
                              hipStream_t stream) {
    const float* x  = (const float*)d_in[0];   // [n, 54]
    const int*   ei = (const int*)d_in[1];     // [2, E]
    const float* W1 = (const float*)d_in[2];   // [54, 16]
    const float* b1 = (const float*)d_in[3];   // [16]
    const float* W2 = (const float*)d_in[4];   // [16, 16]
    const float* b2 = (const float*)d_in[5];   // [16]
    float* out = (float*)d_out;

    const int E = in_sizes[1] / 2;             // 3,200,000
    const int n = in_sizes[0] / FIN;           // 100,000
    const int* src = ei;
    const int* dst = ei + E;
    const int nb = (n + BNODES - 1) >> BSHIFT; // 782 buckets
    const int M = nb * NB_BLK;                 // 200,192 cells (M % 256 == 0)

    char* w = (char*)d_ws;
    auto take = [&](size_t bytes) { char* p = w; w += (bytes + 255) & ~(size_t)255; return p; };
    float* dinv     = (float*)take((size_t)n * 4);
    int*   gh       = (int*)take((size_t)(M + 1) * 4);
    int*   bsum     = (int*)take(512 * 4);
    int*   segstart = (int*)take(1024 * 4);
    int*   btot     = (int*)take(1024 * 4);
    int*   c0       = (int*)take(1024 * 4);
    int*   cs       = (int*)take((size_t)n * 4);
    // shared region: binned (padded, build) then hA/hB fp16 (layers)
    size_t binned_sz = ((size_t)E + 15 * (size_t)M + 16) * 4;
    size_t h_sz      = (size_t)n * HDIM * 2 * 2;
    char*  X        = take(binned_sz > h_sz ? binned_sz : h_sz);
    unsigned int* binned = (unsigned int*)X;
    __half* hA      = (__half*)X;
    __half* hB      = (__half*)(X + (size_t)n * HDIM * 2);
    unsigned int* col = (unsigned int*)take((size_t)E * 4);

    const int B = 256;
    const int nscan = (M + 1 + 4095) >> 12;    // 49

    // --- build: two-level counting sort (64B-aligned cells) -> CSR + dinv ---
    hipMemsetAsync(btot, 0, 1024 * 4, stream);
    hist_kernel<<<NB_BLK, FBT, 0, stream>>>(dst, gh, btot, E, nb, M);
    scan1_kernel<<<nscan, 256, 0, stream>>>(gh, bsum, M + 1);
    scan2_kernel<<<1, 512, 0, stream>>>(bsum, nscan);
    scan3_kernel<<<(M + 1 + B - 1) / B, B, 0, stream>>>(gh, bsum, segstart, M + 1);
    scanb_kernel<<<1, 1024, 0, stream>>>(btot, c0, nb, E);
    fill_binned_kernel<<<NB_BLK, FBT, 0, stream>>>(src, dst, gh, binned, E, nb);
    local_sort_kernel<<<nb, LST, 0, stream>>>(binned, segstart, c0, col, cs, dinv, n);

    // --- layer 1 transform (pre-scaled by dinv, fp16 out); binned dead ---
    gemm_kernel<<<(n + GTILE - 1) / GTILE, B, 0, stream>>>(x, W1, dinv, hA, n);

    // --- layer 1 gather + relu + fused @W2 (pre-scaled, fp16) -> hB ---
    gather_kernel<true><<<(n * 4 + B - 1) / B, B, 0, stream>>>(
        col, cs, hA, dinv, b1, W2, hB, nullptr, n, E);

    // --- layer 2 gather + bias + relu -> out (f32) ---
    gather_kernel<false><<<(n * 4 + B - 1) / B, B, 0, stream>>>(
        col, cs, hB, dinv, b2, nullptr, nullptr, (float4*)out, n, E);
}

// Round 14
// 134.391 us; speedup vs baseline: 1.0500x; 1.0500x over previous
//
#include <hip/hip_runtime.h>
#include <hip/hip_fp16.h>

#define HDIM 16
#define FIN 54
#define BSHIFT 7                  // 128 nodes per bucket
#define BNODES (1 << BSHIFT)      // 128
#define NB_BLK 512                // binning blocks == histogram columns
#define FBT 1024                  // threads in hist/fill blocks
#define LST 512                   // threads in local_sort blocks
#define CAP 6144                  // LDS stage entries in local_sort (24 KB)
#define GTILE 256                 // rows per gemm block
#define GPAD 55                   // padded row stride in LDS (gcd(55,32)=1)

// ---------------------------------------------------------------------------
// pass A1: per-(bucket,block) histogram of dst>>7, int4-vectorized loads
// ---------------------------------------------------------------------------
__global__ __launch_bounds__(FBT)
void hist_kernel(const int* __restrict__ dst, int* __restrict__ gh, int E, int nb) {
    __shared__ int lh[800];                 // nb = 782 <= 800
    for (int t = threadIdx.x; t < nb; t += FBT) lh[t] = 0;
    __syncthreads();
    int per = (((E + NB_BLK - 1) / NB_BLK) + 3) & ~3;
    int s0 = blockIdx.x * per;              // multiple of 4
    int s1 = min(E, s0 + per);
    int idx = s0 + (threadIdx.x << 2);
    for (; idx + 3 < s1; idx += (FBT << 2)) {
        int4 d4 = *(const int4*)&dst[idx];
        atomicAdd(&lh[d4.x >> BSHIFT], 1);
        atomicAdd(&lh[d4.y >> BSHIFT], 1);
        atomicAdd(&lh[d4.z >> BSHIFT], 1);
        atomicAdd(&lh[d4.w >> BSHIFT], 1);
    }
    if (idx < s1) {
        int stop = min(idx + 4, s1);
        for (int e = idx; e < stop; ++e) atomicAdd(&lh[dst[e] >> BSHIFT], 1);
    }
    __syncthreads();
    for (int t = threadIdx.x; t < nb; t += FBT)
        gh[t * NB_BLK + blockIdx.x] = lh[t];
}

// ---------------------------------------------------------------------------
// generic exclusive scan (in place), 256 threads x 16 = 4096 elems per block
// ---------------------------------------------------------------------------
__global__ void scan1_kernel(int* __restrict__ data, int* __restrict__ bsum, int n) {
    __shared__ int sh[256];
    int off = blockIdx.x * 4096 + threadIdx.x * 16;
    int vals[16];
    int local = 0;
#pragma unroll
    for (int k = 0; k < 16; ++k) {
        int v = (off + k < n) ? data[off + k] : 0;
        vals[k] = v;
        local += v;
    }
    sh[threadIdx.x] = local;
    __syncthreads();
#pragma unroll
    for (int d = 1; d < 256; d <<= 1) {
        int t = (threadIdx.x >= d) ? sh[threadIdx.x - d] : 0;
        __syncthreads();
        sh[threadIdx.x] += t;
        __syncthreads();
    }
    int run = (threadIdx.x == 0) ? 0 : sh[threadIdx.x - 1];
#pragma unroll
    for (int k = 0; k < 16; ++k) {
        if (off + k < n) data[off + k] = run;
        run += vals[k];
    }
    if (threadIdx.x == 0) bsum[blockIdx.x] = sh[255];
}

__global__ void scan2_kernel(int* __restrict__ bsum, int nb) {
    __shared__ int sh[512];
    int v = (threadIdx.x < nb) ? bsum[threadIdx.x] : 0;
    sh[threadIdx.x] = v;
    __syncthreads();
    for (int d = 1; d < 512; d <<= 1) {
        int t = (threadIdx.x >= d) ? sh[threadIdx.x - d] : 0;
        __syncthreads();
        sh[threadIdx.x] += t;
        __syncthreads();
    }
    int excl = (threadIdx.x == 0) ? 0 : sh[threadIdx.x - 1];
    if (threadIdx.x < nb) bsum[threadIdx.x] = excl;
}

// scan finalize + fused segstart extraction (bucket start = gh[b*NB_BLK])
__global__ void scan3_kernel(int* __restrict__ data, const int* __restrict__ bsum,
                             int* __restrict__ segstart, int nb, int E, int M) {
    int i = blockIdx.x * blockDim.x + threadIdx.x;
    if (i < M) {
        int v = data[i] + bsum[i >> 12];
        data[i] = v;
        if ((i & (NB_BLK - 1)) == 0) segstart[i / NB_BLK] = v;
    }
    if (i == 0) segstart[nb] = E;
}

// ---------------------------------------------------------------------------
// pass A2: place edges into per-(bucket,block) contiguous cells.
// binned[pos] = (src<<7) | dstLow.  int4-vectorized input loads.
// ---------------------------------------------------------------------------
__global__ __launch_bounds__(FBT)
void fill_binned_kernel(const int* __restrict__ src, const int* __restrict__ dst,
                        const int* __restrict__ gh,
                        unsigned int* __restrict__ binned, int E, int nb) {
    __shared__ int lcur[800];
    for (int t = threadIdx.x; t < nb; t += FBT)
        lcur[t] = gh[t * NB_BLK + blockIdx.x];
    __syncthreads();
    int per = (((E + NB_BLK - 1) / NB_BLK) + 3) & ~3;
    int s0 = blockIdx.x * per;
    int s1 = min(E, s0 + per);
    int idx = s0 + (threadIdx.x << 2);
    for (; idx + 3 < s1; idx += (FBT << 2)) {
        int4 d4 = *(const int4*)&dst[idx];
        int4 v4 = *(const int4*)&src[idx];
        int p0 = atomicAdd(&lcur[d4.x >> BSHIFT], 1);
        int p1 = atomicAdd(&lcur[d4.y >> BSHIFT], 1);
        int p2 = atomicAdd(&lcur[d4.z >> BSHIFT], 1);
        int p3 = atomicAdd(&lcur[d4.w >> BSHIFT], 1);
        binned[p0] = ((unsigned int)v4.x << BSHIFT) | (unsigned int)(d4.x & (BNODES - 1));
        binned[p1] = ((unsigned int)v4.y << BSHIFT) | (unsigned int)(d4.y & (BNODES - 1));
        binned[p2] = ((unsigned int)v4.z << BSHIFT) | (unsigned int)(d4.z & (BNODES - 1));
        binned[p3] = ((unsigned int)v4.w << BSHIFT) | (unsigned int)(d4.w & (BNODES - 1));
    }
    if (idx < s1) {
        int stop = min(idx + 4, s1);
        for (int e = idx; e < stop; ++e) {
            int d = dst[e];
            int pos = atomicAdd(&lcur[d >> BSHIFT], 1);
            binned[pos] = ((unsigned int)src[e] << BSHIFT) | (unsigned int)(d & (BNODES - 1));
        }
    }
}

// ---------------------------------------------------------------------------
// pass B: per-bucket counting sort to full CSR order via LDS staging.
// Also emits per-node dinv and CSR starts.
// ---------------------------------------------------------------------------
__global__ __launch_bounds__(LST)
void local_sort_kernel(const unsigned int* __restrict__ binned,
                       const int* __restrict__ segstart,
                       unsigned int* __restrict__ col, int* __restrict__ cs,
                       float* __restrict__ dinv, int n) {
    __shared__ unsigned int stage[CAP];     // 24 KB
    __shared__ int hist[BNODES], scn[BNODES], cur[BNODES];
    int b = blockIdx.x;
    int s0 = segstart[b], s1 = segstart[b + 1];
    int t = threadIdx.x;

    if (t < BNODES) hist[t] = 0;
    __syncthreads();
    for (int k = s0 + t; k < s1; k += LST)
        atomicAdd(&hist[binned[k] & (BNODES - 1)], 1);
    __syncthreads();
    if (t < BNODES) scn[t] = hist[t];
    __syncthreads();
    for (int d = 1; d < BNODES; d <<= 1) {
        int v = (t < BNODES && t >= d) ? scn[t - d] : 0;
        __syncthreads();
        if (t < BNODES) scn[t] += v;
        __syncthreads();
    }
    if (t < BNODES) {
        int excl = scn[t] - hist[t];        // exclusive scan
        cur[t] = excl;
        int node = (b << BSHIFT) + t;
        if (node < n) {
            cs[node] = s0 + excl;
            dinv[node] = rsqrtf((float)hist[t] + 1.0f);
        }
    }
    __syncthreads();
    for (int k = s0 + t; k < s1; k += LST) {
        unsigned int p = binned[k];
        int pos = atomicAdd(&cur[p & (BNODES - 1)], 1);
        unsigned int sv = p >> BSHIFT;
        if (pos < CAP) stage[pos] = sv;
        else col[s0 + pos] = sv;            // statistically-never overflow path
    }
    __syncthreads();
    int len = s1 - s0;
    if (len > CAP) len = CAP;
    for (int k = t; k < len; k += LST) col[s0 + k] = stage[k];   // coalesced
}

// ---------------------------------------------------------------------------
// hA[row,:] = fp16( dinv[row] * (x[row,:] @ W1) ), x staged in LDS coalesced
// ---------------------------------------------------------------------------
__global__ __launch_bounds__(256)
void gemm_kernel(const float* __restrict__ X, const float* __restrict__ W,
                 const float* __restrict__ dinv, __half* __restrict__ Yh, int n) {
    __shared__ float Wl[FIN * HDIM];       // 3456 B
    __shared__ float xl[GTILE * GPAD];     // 56320 B
    for (int t = threadIdx.x; t < FIN * HDIM; t += blockDim.x) Wl[t] = W[t];

    int base = blockIdx.x * GTILE;
    int nrows = min(GTILE, n - base);
    const float* xb = X + (size_t)base * FIN;
    int tot = nrows * FIN;
    for (int i4 = threadIdx.x; i4 < (tot >> 2); i4 += blockDim.x) {
        float4 v = ((const float4*)xb)[i4];
        int i = i4 << 2;
        int r = i / FIN;
        int c = i - r * FIN;
#pragma unroll
        for (int u = 0; u < 4; ++u) {
            int cc = c + u, rr = r;
            if (cc >= FIN) { cc -= FIN; ++rr; }
            xl[rr * GPAD + cc] = (&v.x)[u];
        }
    }
    for (int i = (tot & ~3) + threadIdx.x; i < tot; i += blockDim.x) {
        int r = i / FIN;
        xl[r * GPAD + (i - r * FIN)] = xb[i];
    }
    __syncthreads();

    int t = threadIdx.x;
    if (t < nrows) {
        int row = base + t;
        const float* xr = &xl[t * GPAD];
        float acc[HDIM];
#pragma unroll
        for (int j = 0; j < HDIM; ++j) acc[j] = 0.0f;
#pragma unroll
        for (int k = 0; k < FIN; ++k) {
            float xv = xr[k];
#pragma unroll
            for (int j = 0; j < HDIM; ++j)
                acc[j] = fmaf(xv, Wl[k * HDIM + j], acc[j]);
        }
        float di = dinv[row];
        __half2 hh[8];
#pragma unroll
        for (int j = 0; j < 8; ++j)
            hh[j] = __floats2half2_rn(di * acc[2 * j], di * acc[2 * j + 1]);
        uint4* yo = (uint4*)(Yh + ((size_t)row << 4));
        yo[0] = *(uint4*)&hh[0];
        yo[1] = *(uint4*)&hh[4];
    }
}

// ---------------------------------------------------------------------------
// Gather: 4 lanes per node; hs in fp16 (32 B/node -> 3.2 MB, L2-resident).
//   acc4 = hs[i] + sum_{s in N(i)} hs[s]   (f32 accumulation, unroll-8)
//   r4   = relu(dinv_i * acc4 + bias)
//   FUSE_W2: outh[i] = fp16(dinv_i * (r @ W2));  else out4[i] = r (f32)
// ---------------------------------------------------------------------------
__device__ __forceinline__ float4 ld_h4(const __half* __restrict__ hsh,
                                        unsigned int node, int q) {
    const __half2* p = (const __half2*)(hsh + ((size_t)node << 4) + (q << 2));
    float2 fa = __half22float2(p[0]);
    float2 fb = __half22float2(p[1]);
    return make_float4(fa.x, fa.y, fb.x, fb.y);
}

template <bool FUSE_W2>
__global__ void gather_kernel(const unsigned int* __restrict__ col, const int* __restrict__ cs,
                              const __half* __restrict__ hsh, const float* __restrict__ dinv,
                              const float* __restrict__ bias, const float* __restrict__ W2,
                              __half* __restrict__ outh, float4* __restrict__ out4,
                              int n, int E) {
    __shared__ float4 W2l[HDIM * 4];   // W2l[jj*4+q] = W2[jj][4q..4q+3]
    if constexpr (FUSE_W2) {
        for (int t = threadIdx.x; t < HDIM * 4; t += blockDim.x)
            W2l[t] = ((const float4*)W2)[t];
        __syncthreads();
    }
    int idx = blockIdx.x * blockDim.x + threadIdx.x;
    int i = idx >> 2;
    int q = idx & 3;
    if (i >= n) return;
    int start = cs[i];
    int end = (i + 1 < n) ? cs[i + 1] : E;

    float4 acc = ld_h4(hsh, (unsigned int)i, q);   // self-loop term
    int k = start;
    for (; k + 7 < end; k += 8) {
        unsigned int s[8];
#pragma unroll
        for (int u = 0; u < 8; ++u) s[u] = col[k + u];
        float4 h[8];
#pragma unroll
        for (int u = 0; u < 8; ++u) h[u] = ld_h4(hsh, s[u], q);
#pragma unroll
        for (int u = 0; u < 8; ++u) {
            acc.x += h[u].x; acc.y += h[u].y; acc.z += h[u].z; acc.w += h[u].w;
        }
    }
    for (; k < end; ++k) {
        float4 h = ld_h4(hsh, col[k], q);
        acc.x += h.x; acc.y += h.y; acc.z += h.z; acc.w += h.w;
    }

    float di = dinv[i];
    float4 b4 = ((const float4*)bias)[q];
    float4 r;
    r.x = fmaxf(fmaf(di, acc.x, b4.x), 0.0f);
    r.y = fmaxf(fmaf(di, acc.y, b4.y), 0.0f);
    r.z = fmaxf(fmaf(di, acc.z, b4.z), 0.0f);
    r.w = fmaxf(fmaf(di, acc.w, b4.w), 0.0f);

    if constexpr (FUSE_W2) {
        int lane = threadIdx.x & 63;
        int base = lane & ~3;
        float4 o = make_float4(0.f, 0.f, 0.f, 0.f);
#pragma unroll
        for (int p = 0; p < 4; ++p) {
            float rx = __shfl(r.x, base + p, 64);
            float ry = __shfl(r.y, base + p, 64);
            float rz = __shfl(r.z, base + p, 64);
            float rw = __shfl(r.w, base + p, 64);
            float4 w0 = W2l[(p * 4 + 0) * 4 + q];
            float4 w1 = W2l[(p * 4 + 1) * 4 + q];
            float4 w2 = W2l[(p * 4 + 2) * 4 + q];
            float4 w3 = W2l[(p * 4 + 3) * 4 + q];
            o.x = fmaf(rx, w0.x, fmaf(ry, w1.x, fmaf(rz, w2.x, fmaf(rw, w3.x, o.x))));
            o.y = fmaf(rx, w0.y, fmaf(ry, w1.y, fmaf(rz, w2.y, fmaf(rw, w3.y, o.y))));
            o.z = fmaf(rx, w0.z, fmaf(ry, w1.z, fmaf(rz, w2.z, fmaf(rw, w3.z, o.z))));
            o.w = fmaf(rx, w0.w, fmaf(ry, w1.w, fmaf(rz, w2.w, fmaf(rw, w3.w, o.w))));
        }
        __half2 o01 = __floats2half2_rn(di * o.x, di * o.y);
        __half2 o23 = __floats2half2_rn(di * o.z, di * o.w);
        uint2 pk;
        pk.x = *(unsigned int*)&o01;
        pk.y = *(unsigned int*)&o23;
        *(uint2*)(outh + ((size_t)i << 4) + (q << 2)) = pk;
    } else {
        out4[(size_t)i * 4 + q] = r;
    }
}

extern "C" void kernel_launch(void* const* d_in, const int* in_sizes, int n_in,
                              void* d_out, int out_size, void* d_ws, size_t ws_size,
                              hipStream_t stream) {
    const float* x  = (const float*)d_in[0];   // [n, 54]
    const int*   ei = (const int*)d_in[1];     // [2, E]
    const float* W1 = (const float*)d_in[2];   // [54, 16]
    const float* b1 = (const float*)d_in[3];   // [16]
    const float* W2 = (const float*)d_in[4];   // [16, 16]
    const float* b2 = (const float*)d_in[5];   // [16]
    float* out = (float*)d_out;

    const int E = in_sizes[1] / 2;             // 3,200,000
    const int n = in_sizes[0] / FIN;           // 100,000
    const int* src = ei;
    const int* dst = ei + E;
    const int nb = (n + BNODES - 1) >> BSHIFT; // 782 buckets
    const int M = nb * NB_BLK;                 // 400,384 counters

    char* w = (char*)d_ws;
    float* dinv     = (float*)w;               w += (size_t)n * 4;
    int*   gh       = (int*)w;                 w += (size_t)M * 4;
    int*   bsum     = (int*)w;                 w += 512 * 4;
    int*   segstart = (int*)w;                 w += 1024 * 4;
    int*   cs       = (int*)w;                 w += (size_t)n * 4;
    char*  X        = w;                       // 12.8 MB shared region:
    unsigned int* binned = (unsigned int*)X;   //   build: binned[E]
    __half* hA      = (__half*)X;              //   later: hA[16n] fp16 (binned dead)
    __half* hB      = (__half*)(X + (size_t)n * HDIM * 2);
    {
        size_t xsz = (size_t)E * 4;
        size_t hsz = (size_t)n * HDIM * 4;     // hA+hB fp16
        w = X + (xsz > hsz ? xsz : hsz);
    }
    unsigned int* col = (unsigned int*)w;      // E u32 (12.8 MB)

    const int B = 256;
    const int nscan = (M + 4095) >> 12;        // 98

    // --- build: two-level counting sort -> CSR (col, cs) + dinv ---
    hist_kernel<<<NB_BLK, FBT, 0, stream>>>(dst, gh, E, nb);
    scan1_kernel<<<nscan, 256, 0, stream>>>(gh, bsum, M);
    scan2_kernel<<<1, 512, 0, stream>>>(bsum, nscan);
    scan3_kernel<<<(M + B - 1) / B, B, 0, stream>>>(gh, bsum, segstart, nb, E, M);
    fill_binned_kernel<<<NB_BLK, FBT, 0, stream>>>(src, dst, gh, binned, E, nb);
    local_sort_kernel<<<nb, LST, 0, stream>>>(binned, segstart, col, cs, dinv, n);

    // --- layer 1 transform (pre-scaled by dinv, fp16 out); binned dead ---
    gemm_kernel<<<(n + GTILE - 1) / GTILE, B, 0, stream>>>(x, W1, dinv, hA, n);

    // --- layer 1 gather + relu + fused @W2 (pre-scaled, fp16) -> hB ---
    gather_kernel<true><<<(n * 4 + B - 1) / B, B, 0, stream>>>(
        col, cs, hA, dinv, b1, W2, hB, nullptr, n, E);

    // --- layer 2 gather + bias + relu -> out (f32) ---
    gather_kernel<false><<<(n * 4 + B - 1) / B, B, 0, stream>>>(
        col, cs, hB, dinv, b2, nullptr, nullptr, (float4*)out, n, E);
}

// Round 15
// 118.966 us; speedup vs baseline: 1.1861x; 1.1297x over previous
//
#include <hip/hip_runtime.h>
#include <hip/hip_fp16.h>

#define HDIM 16
#define FIN 54
#define BSHIFT 7                  // 128 nodes per bucket
#define BNODES (1 << BSHIFT)      // 128
#define NB_BLK 256                // binning blocks == histogram columns
#define NBMAXB 800                // LDS bucket arrays (nb = 782)
#define FBT 1024                  // threads in hist/fill blocks
#define LST 512                   // threads in local_sort blocks
#define CAP 6144                  // LDS stage entries in local_sort (24 KB)
#define FPE 12544                 // LDS stage entries in fill (50 KB), >= per
#define GTILE 256                 // rows per gemm block
#define GPAD 55                   // padded row stride in LDS (gcd(55,32)=1)

// ---------------------------------------------------------------------------
// pass A1: per-(bucket,block) histogram of dst>>7, int4-vectorized loads
// ---------------------------------------------------------------------------
__global__ __launch_bounds__(FBT)
void hist_kernel(const int* __restrict__ dst, int* __restrict__ gh, int E, int nb) {
    __shared__ int lh[NBMAXB];
    for (int t = threadIdx.x; t < nb; t += FBT) lh[t] = 0;
    __syncthreads();
    int per = (((E + NB_BLK - 1) / NB_BLK) + 3) & ~3;
    int s0 = blockIdx.x * per;              // multiple of 4
    int s1 = min(E, s0 + per);
    int idx = s0 + (threadIdx.x << 2);
    for (; idx + 3 < s1; idx += (FBT << 2)) {
        int4 d4 = *(const int4*)&dst[idx];
        atomicAdd(&lh[d4.x >> BSHIFT], 1);
        atomicAdd(&lh[d4.y >> BSHIFT], 1);
        atomicAdd(&lh[d4.z >> BSHIFT], 1);
        atomicAdd(&lh[d4.w >> BSHIFT], 1);
    }
    if (idx < s1) {
        int stop = min(idx + 4, s1);
        for (int e = idx; e < stop; ++e) atomicAdd(&lh[dst[e] >> BSHIFT], 1);
    }
    __syncthreads();
    for (int t = threadIdx.x; t < nb; t += FBT)
        gh[t * NB_BLK + blockIdx.x] = lh[t];
}

// ---------------------------------------------------------------------------
// generic exclusive scan (in place), 256 threads x 16 = 4096 elems per block
// ---------------------------------------------------------------------------
__global__ void scan1_kernel(int* __restrict__ data, int* __restrict__ bsum, int n) {
    __shared__ int sh[256];
    int off = blockIdx.x * 4096 + threadIdx.x * 16;
    int vals[16];
    int local = 0;
#pragma unroll
    for (int k = 0; k < 16; ++k) {
        int v = (off + k < n) ? data[off + k] : 0;
        vals[k] = v;
        local += v;
    }
    sh[threadIdx.x] = local;
    __syncthreads();
#pragma unroll
    for (int d = 1; d < 256; d <<= 1) {
        int t = (threadIdx.x >= d) ? sh[threadIdx.x - d] : 0;
        __syncthreads();
        sh[threadIdx.x] += t;
        __syncthreads();
    }
    int run = (threadIdx.x == 0) ? 0 : sh[threadIdx.x - 1];
#pragma unroll
    for (int k = 0; k < 16; ++k) {
        if (off + k < n) data[off + k] = run;
        run += vals[k];
    }
    if (threadIdx.x == 0) bsum[blockIdx.x] = sh[255];
}

__global__ void scan2_kernel(int* __restrict__ bsum, int nb) {
    __shared__ int sh[512];
    int v = (threadIdx.x < nb) ? bsum[threadIdx.x] : 0;
    sh[threadIdx.x] = v;
    __syncthreads();
    for (int d = 1; d < 512; d <<= 1) {
        int t = (threadIdx.x >= d) ? sh[threadIdx.x - d] : 0;
        __syncthreads();
        sh[threadIdx.x] += t;
        __syncthreads();
    }
    int excl = (threadIdx.x == 0) ? 0 : sh[threadIdx.x - 1];
    if (threadIdx.x < nb) bsum[threadIdx.x] = excl;
}

// scan finalize + fused segstart extraction (bucket start = gh[b*NB_BLK])
__global__ void scan3_kernel(int* __restrict__ data, const int* __restrict__ bsum,
                             int* __restrict__ segstart, int nb, int E, int M) {
    int i = blockIdx.x * blockDim.x + threadIdx.x;
    if (i < M) {
        int v = data[i] + bsum[i >> 12];
        data[i] = v;
        if ((i & (NB_BLK - 1)) == 0) segstart[i / NB_BLK] = v;
    }
    if (i == 0) segstart[nb] = E;
}

// ---------------------------------------------------------------------------
// pass A2: LDS-staged binning with COALESCED global writes.
//   pass1: local bucket histogram; LDS scan -> local offsets
//   pass2: place packed (src<<7|dstLow) into LDS stage via cursors
//   flush: one wave per bucket copies each cell stage->binned contiguously
// ---------------------------------------------------------------------------
__global__ __launch_bounds__(FBT)
void fill_binned_kernel(const int* __restrict__ src, const int* __restrict__ dst,
                        const int* __restrict__ gh,
                        unsigned int* __restrict__ binned, int E, int nb) {
    __shared__ unsigned int stage[FPE];     // 50 KB
    __shared__ int lh[NBMAXB], lcur[NBMAXB], gcur[NBMAXB];
    __shared__ int ls[FBT];
    int per = (((E + NB_BLK - 1) / NB_BLK) + 3) & ~3;
    int s0 = blockIdx.x * per;
    int s1 = min(E, s0 + per);
    int t = threadIdx.x;
    for (int b = t; b < nb; b += FBT)
        gcur[b] = gh[b * NB_BLK + blockIdx.x];   // global cell cursors
    // chunk loop (single iteration when per <= FPE)
    for (int c0 = s0; c0 < s1; c0 += FPE) {
        int c1 = min(s1, c0 + FPE);
        for (int b = t; b < nb; b += FBT) lh[b] = 0;
        __syncthreads();
        // pass 1: local histogram
        int idx = c0 + (t << 2);
        for (; idx + 3 < c1; idx += (FBT << 2)) {
            int4 d4 = *(const int4*)&dst[idx];
            atomicAdd(&lh[d4.x >> BSHIFT], 1);
            atomicAdd(&lh[d4.y >> BSHIFT], 1);
            atomicAdd(&lh[d4.z >> BSHIFT], 1);
            atomicAdd(&lh[d4.w >> BSHIFT], 1);
        }
        if (idx < c1) {
            int stop = min(idx + 4, c1);
            for (int e = idx; e < stop; ++e) atomicAdd(&lh[dst[e] >> BSHIFT], 1);
        }
        __syncthreads();
        // inclusive scan over buckets (Hillis-Steele on FBT lanes)
        ls[t] = (t < nb) ? lh[t] : 0;
        __syncthreads();
        for (int d = 1; d < FBT; d <<= 1) {
            int v = (t >= d) ? ls[t - d] : 0;
            __syncthreads();
            ls[t] += v;
            __syncthreads();
        }
        if (t < nb) lcur[t] = ls[t] - lh[t];    // exclusive start = cursor
        __syncthreads();
        // pass 2: place into stage
        idx = c0 + (t << 2);
        for (; idx + 3 < c1; idx += (FBT << 2)) {
            int4 d4 = *(const int4*)&dst[idx];
            int4 v4 = *(const int4*)&src[idx];
            int p0 = atomicAdd(&lcur[d4.x >> BSHIFT], 1);
            int p1 = atomicAdd(&lcur[d4.y >> BSHIFT], 1);
            int p2 = atomicAdd(&lcur[d4.z >> BSHIFT], 1);
            int p3 = atomicAdd(&lcur[d4.w >> BSHIFT], 1);
            stage[p0] = ((unsigned int)v4.x << BSHIFT) | (unsigned int)(d4.x & (BNODES - 1));
            stage[p1] = ((unsigned int)v4.y << BSHIFT) | (unsigned int)(d4.y & (BNODES - 1));
            stage[p2] = ((unsigned int)v4.z << BSHIFT) | (unsigned int)(d4.z & (BNODES - 1));
            stage[p3] = ((unsigned int)v4.w << BSHIFT) | (unsigned int)(d4.w & (BNODES - 1));
        }
        if (idx < c1) {
            int stop = min(idx + 4, c1);
            for (int e = idx; e < stop; ++e) {
                int d = dst[e];
                int pos = atomicAdd(&lcur[d >> BSHIFT], 1);
                stage[pos] = ((unsigned int)src[e] << BSHIFT) | (unsigned int)(d & (BNODES - 1));
            }
        }
        __syncthreads();
        // flush: wave w copies buckets w, w+16, ... (consecutive lanes ->
        // consecutive global addresses within each cell)
        int wid = t >> 6, lane = t & 63;
        for (int b = wid; b < nb; b += (FBT >> 6)) {
            int len = lh[b];
            int lsrc = lcur[b] - len;           // local cell start
            int g0 = gcur[b];
            for (int l = lane; l < len; l += 64)
                binned[g0 + l] = stage[lsrc + l];
        }
        __syncthreads();
        for (int b = t; b < nb; b += FBT) gcur[b] += lh[b];
        __syncthreads();
    }
}

// ---------------------------------------------------------------------------
// pass B: per-bucket counting sort to full CSR order via LDS staging.
// Also emits per-node dinv and CSR starts.
// ---------------------------------------------------------------------------
__global__ __launch_bounds__(LST)
void local_sort_kernel(const unsigned int* __restrict__ binned,
                       const int* __restrict__ segstart,
                       unsigned int* __restrict__ col, int* __restrict__ cs,
                       float* __restrict__ dinv, int n) {
    __shared__ unsigned int stage[CAP];     // 24 KB
    __shared__ int hist[BNODES], scn[BNODES], cur[BNODES];
    int b = blockIdx.x;
    int s0 = segstart[b], s1 = segstart[b + 1];
    int t = threadIdx.x;

    if (t < BNODES) hist[t] = 0;
    __syncthreads();
    for (int k = s0 + t; k < s1; k += LST)
        atomicAdd(&hist[binned[k] & (BNODES - 1)], 1);
    __syncthreads();
    if (t < BNODES) scn[t] = hist[t];
    __syncthreads();
    for (int d = 1; d < BNODES; d <<= 1) {
        int v = (t < BNODES && t >= d) ? scn[t - d] : 0;
        __syncthreads();
        if (t < BNODES) scn[t] += v;
        __syncthreads();
    }
    if (t < BNODES) {
        int excl = scn[t] - hist[t];        // exclusive scan
        cur[t] = excl;
        int node = (b << BSHIFT) + t;
        if (node < n) {
            cs[node] = s0 + excl;
            dinv[node] = rsqrtf((float)hist[t] + 1.0f);
        }
    }
    __syncthreads();
    for (int k = s0 + t; k < s1; k += LST) {
        unsigned int p = binned[k];
        int pos = atomicAdd(&cur[p & (BNODES - 1)], 1);
        unsigned int sv = p >> BSHIFT;
        if (pos < CAP) stage[pos] = sv;
        else col[s0 + pos] = sv;            // statistically-never overflow path
    }
    __syncthreads();
    int len = s1 - s0;
    if (len > CAP) len = CAP;
    for (int k = t; k < len; k += LST) col[s0 + k] = stage[k];   // coalesced
}

// ---------------------------------------------------------------------------
// hA[row,:] = fp16( dinv[row] * (x[row,:] @ W1) ), x staged in LDS coalesced
// ---------------------------------------------------------------------------
__global__ __launch_bounds__(256)
void gemm_kernel(const float* __restrict__ X, const float* __restrict__ W,
                 const float* __restrict__ dinv, __half* __restrict__ Yh, int n) {
    __shared__ float Wl[FIN * HDIM];       // 3456 B
    __shared__ float xl[GTILE * GPAD];     // 56320 B
    for (int t = threadIdx.x; t < FIN * HDIM; t += blockDim.x) Wl[t] = W[t];

    int base = blockIdx.x * GTILE;
    int nrows = min(GTILE, n - base);
    const float* xb = X + (size_t)base * FIN;
    int tot = nrows * FIN;
    for (int i4 = threadIdx.x; i4 < (tot >> 2); i4 += blockDim.x) {
        float4 v = ((const float4*)xb)[i4];
        int i = i4 << 2;
        int r = i / FIN;
        int c = i - r * FIN;
#pragma unroll
        for (int u = 0; u < 4; ++u) {
            int cc = c + u, rr = r;
            if (cc >= FIN) { cc -= FIN; ++rr; }
            xl[rr * GPAD + cc] = (&v.x)[u];
        }
    }
    for (int i = (tot & ~3) + threadIdx.x; i < tot; i += blockDim.x) {
        int r = i / FIN;
        xl[r * GPAD + (i - r * FIN)] = xb[i];
    }
    __syncthreads();

    int t = threadIdx.x;
    if (t < nrows) {
        int row = base + t;
        const float* xr = &xl[t * GPAD];
        float acc[HDIM];
#pragma unroll
        for (int j = 0; j < HDIM; ++j) acc[j] = 0.0f;
#pragma unroll
        for (int k = 0; k < FIN; ++k) {
            float xv = xr[k];
#pragma unroll
            for (int j = 0; j < HDIM; ++j)
                acc[j] = fmaf(xv, Wl[k * HDIM + j], acc[j]);
        }
        float di = dinv[row];
        __half2 hh[8];
#pragma unroll
        for (int j = 0; j < 8; ++j)
            hh[j] = __floats2half2_rn(di * acc[2 * j], di * acc[2 * j + 1]);
        uint4* yo = (uint4*)(Yh + ((size_t)row << 4));
        yo[0] = *(uint4*)&hh[0];
        yo[1] = *(uint4*)&hh[4];
    }
}

// ---------------------------------------------------------------------------
// Gather: 4 lanes per node; hs in fp16 (32 B/node -> 3.2 MB, L2-resident).
//   acc4 = hs[i] + sum_{s in N(i)} hs[s]   (f32 accumulation, unroll-8)
//   r4   = relu(dinv_i * acc4 + bias)
//   FUSE_W2: outh[i] = fp16(dinv_i * (r @ W2));  else out4[i] = r (f32)
// ---------------------------------------------------------------------------
__device__ __forceinline__ float4 ld_h4(const __half* __restrict__ hsh,
                                        unsigned int node, int q) {
    const __half2* p = (const __half2*)(hsh + ((size_t)node << 4) + (q << 2));
    float2 fa = __half22float2(p[0]);
    float2 fb = __half22float2(p[1]);
    return make_float4(fa.x, fa.y, fb.x, fb.y);
}

template <bool FUSE_W2>
__global__ void gather_kernel(const unsigned int* __restrict__ col, const int* __restrict__ cs,
                              const __half* __restrict__ hsh, const float* __restrict__ dinv,
                              const float* __restrict__ bias, const float* __restrict__ W2,
                              __half* __restrict__ outh, float4* __restrict__ out4,
                              int n, int E) {
    __shared__ float4 W2l[HDIM * 4];   // W2l[jj*4+q] = W2[jj][4q..4q+3]
    if constexpr (FUSE_W2) {
        for (int t = threadIdx.x; t < HDIM * 4; t += blockDim.x)
            W2l[t] = ((const float4*)W2)[t];
        __syncthreads();
    }
    int idx = blockIdx.x * blockDim.x + threadIdx.x;
    int i = idx >> 2;
    int q = idx & 3;
    if (i >= n) return;
    int start = cs[i];
    int end = (i + 1 < n) ? cs[i + 1] : E;

    float4 acc = ld_h4(hsh, (unsigned int)i, q);   // self-loop term
    int k = start;
    for (; k + 7 < end; k += 8) {
        unsigned int s[8];
#pragma unroll
        for (int u = 0; u < 8; ++u) s[u] = col[k + u];
        float4 h[8];
#pragma unroll
        for (int u = 0; u < 8; ++u) h[u] = ld_h4(hsh, s[u], q);
#pragma unroll
        for (int u = 0; u < 8; ++u) {
            acc.x += h[u].x; acc.y += h[u].y; acc.z += h[u].z; acc.w += h[u].w;
        }
    }
    for (; k < end; ++k) {
        float4 h = ld_h4(hsh, col[k], q);
        acc.x += h.x; acc.y += h.y; acc.z += h.z; acc.w += h.w;
    }

    float di = dinv[i];
    float4 b4 = ((const float4*)bias)[q];
    float4 r;
    r.x = fmaxf(fmaf(di, acc.x, b4.x), 0.0f);
    r.y = fmaxf(fmaf(di, acc.y, b4.y), 0.0f);
    r.z = fmaxf(fmaf(di, acc.z, b4.z), 0.0f);
    r.w = fmaxf(fmaf(di, acc.w, b4.w), 0.0f);

    if constexpr (FUSE_W2) {
        int lane = threadIdx.x & 63;
        int base = lane & ~3;
        float4 o = make_float4(0.f, 0.f, 0.f, 0.f);
#pragma unroll
        for (int p = 0; p < 4; ++p) {
            float rx = __shfl(r.x, base + p, 64);
            float ry = __shfl(r.y, base + p, 64);
            float rz = __shfl(r.z, base + p, 64);
            float rw = __shfl(r.w, base + p, 64);
            float4 w0 = W2l[(p * 4 + 0) * 4 + q];
            float4 w1 = W2l[(p * 4 + 1) * 4 + q];
            float4 w2 = W2l[(p * 4 + 2) * 4 + q];
            float4 w3 = W2l[(p * 4 + 3) * 4 + q];
            o.x = fmaf(rx, w0.x, fmaf(ry, w1.x, fmaf(rz, w2.x, fmaf(rw, w3.x, o.x))));
            o.y = fmaf(rx, w0.y, fmaf(ry, w1.y, fmaf(rz, w2.y, fmaf(rw, w3.y, o.y))));
            o.z = fmaf(rx, w0.z, fmaf(ry, w1.z, fmaf(rz, w2.z, fmaf(rw, w3.z, o.z))));
            o.w = fmaf(rx, w0.w, fmaf(ry, w1.w, fmaf(rz, w2.w, fmaf(rw, w3.w, o.w))));
        }
        __half2 o01 = __floats2half2_rn(di * o.x, di * o.y);
        __half2 o23 = __floats2half2_rn(di * o.z, di * o.w);
        uint2 pk;
        pk.x = *(unsigned int*)&o01;
        pk.y = *(unsigned int*)&o23;
        *(uint2*)(outh + ((size_t)i << 4) + (q << 2)) = pk;
    } else {
        out4[(size_t)i * 4 + q] = r;
    }
}

extern "C" void kernel_launch(void* const* d_in, const int* in_sizes, int n_in,
                              void* d_out, int out_size, void* d_ws, size_t ws_size,
                              hipStream_t stream) {
    const float* x  = (const float*)d_in[0];   // [n, 54]
    const int*   ei = (const int*)d_in[1];     // [2, E]
    const float* W1 = (const float*)d_in[2];   // [54, 16]
    const float* b1 = (const float*)d_in[3];   // [16]
    const float* W2 = (const float*)d_in[4];   // [16, 16]
    const float* b2 = (const float*)d_in[5];   // [16]
    float* out = (float*)d_out;

    const int E = in_sizes[1] / 2;             // 3,200,000
    const int n = in_sizes[0] / FIN;           // 100,000
    const int* src = ei;
    const int* dst = ei + E;
    const int nb = (n + BNODES - 1) >> BSHIFT; // 782 buckets
    const int M = nb * NB_BLK;                 // 200,192 counters

    char* w = (char*)d_ws;
    float* dinv     = (float*)w;               w += (size_t)n * 4;
    int*   gh       = (int*)w;                 w += (size_t)M * 4;
    int*   bsum     = (int*)w;                 w += 512 * 4;
    int*   segstart = (int*)w;                 w += 1024 * 4;
    int*   cs       = (int*)w;                 w += (size_t)n * 4;
    char*  X        = w;                       // 12.8 MB shared region:
    unsigned int* binned = (unsigned int*)X;   //   build: binned[E]
    __half* hA      = (__half*)X;              //   later: hA[16n] fp16 (binned dead)
    __half* hB      = (__half*)(X + (size_t)n * HDIM * 2);
    {
        size_t xsz = (size_t)E * 4;
        size_t hsz = (size_t)n * HDIM * 4;     // hA+hB fp16
        w = X + (xsz > hsz ? xsz : hsz);
    }
    unsigned int* col = (unsigned int*)w;      // E u32 (12.8 MB)

    const int B = 256;
    const int nscan = (M + 4095) >> 12;        // 49

    // --- build: two-level counting sort -> CSR (col, cs) + dinv ---
    hist_kernel<<<NB_BLK, FBT, 0, stream>>>(dst, gh, E, nb);
    scan1_kernel<<<nscan, 256, 0, stream>>>(gh, bsum, M);
    scan2_kernel<<<1, 512, 0, stream>>>(bsum, nscan);
    scan3_kernel<<<(M + B - 1) / B, B, 0, stream>>>(gh, bsum, segstart, nb, E, M);
    fill_binned_kernel<<<NB_BLK, FBT, 0, stream>>>(src, dst, gh, binned, E, nb);
    local_sort_kernel<<<nb, LST, 0, stream>>>(binned, segstart, col, cs, dinv, n);

    // --- layer 1 transform (pre-scaled by dinv, fp16 out); binned dead ---
    gemm_kernel<<<(n + GTILE - 1) / GTILE, B, 0, stream>>>(x, W1, dinv, hA, n);

    // --- layer 1 gather + relu + fused @W2 (pre-scaled, fp16) -> hB ---
    gather_kernel<true><<<(n * 4 + B - 1) / B, B, 0, stream>>>(
        col, cs, hA, dinv, b1, W2, hB, nullptr, n, E);

    // --- layer 2 gather + bias + relu -> out (f32) ---
    gather_kernel<false><<<(n * 4 + B - 1) / B, B, 0, stream>>>(
        col, cs, hB, dinv, b2, nullptr, nullptr, (float4*)out, n, E);
}

// Round 16
// 109.709 us; speedup vs baseline: 1.2862x; 1.0844x over previous
//
#include <hip/hip_runtime.h>
#include <hip/hip_fp16.h>

#define HDIM 16
#define FIN 54
#define BSHIFT 7                  // 128 nodes per bucket
#define BNODES (1 << BSHIFT)      // 128
#define NBMAXB 800                // LDS bucket arrays (nb = 782)
#define NBBMAX 512                // max fill blocks supported
#define FBT 1024                  // threads in fill blocks
#define LST 512                   // threads in local_sort blocks
#define FPE 12544                 // LDS stage entries in fill (50 KB)
#define PADCOL 6144               // col slots per bucket (mean 4092 + 32 sigma)
#define GTILE 256                 // rows per gemm block
#define GPAD 55                   // padded row stride in LDS (gcd(55,32)=1)

// ---------------------------------------------------------------------------
// fill: self-contained binning. Block owns binned[blk*per .. blk*per+tot).
//   pass1: LDS bucket histogram (int4 loads)
//   scan : LDS exclusive scan -> local offsets; emit lps[b][blk] (b<=nb)
//   pass2: place packed (src<<7|dstLow) into LDS stage via cursors
//   flush: stage -> binned verbatim (stage is already bucket-sorted locally)
// ---------------------------------------------------------------------------
__global__ __launch_bounds__(FBT)
void fill_binned_kernel(const int* __restrict__ src, const int* __restrict__ dst,
                        int* __restrict__ lps, unsigned int* __restrict__ binned,
                        int E, int nb, int nbb, int per) {
    __shared__ unsigned int stage[FPE];     // 50 KB
    __shared__ int lh[NBMAXB], lcur[NBMAXB];
    __shared__ int ls[FBT];
    int blk = blockIdx.x;
    int s0 = blk * per;
    int s1 = min(E, s0 + per);
    int tot = s1 - s0;
    int t = threadIdx.x;

    for (int b = t; b < nb; b += FBT) lh[b] = 0;
    __syncthreads();
    // pass 1: histogram
    int idx = s0 + (t << 2);
    for (; idx + 3 < s1; idx += (FBT << 2)) {
        int4 d4 = *(const int4*)&dst[idx];
        atomicAdd(&lh[d4.x >> BSHIFT], 1);
        atomicAdd(&lh[d4.y >> BSHIFT], 1);
        atomicAdd(&lh[d4.z >> BSHIFT], 1);
        atomicAdd(&lh[d4.w >> BSHIFT], 1);
    }
    if (idx < s1) {
        int stop = min(idx + 4, s1);
        for (int e = idx; e < stop; ++e) atomicAdd(&lh[dst[e] >> BSHIFT], 1);
    }
    __syncthreads();
    // inclusive scan over buckets
    ls[t] = (t < nb) ? lh[t] : 0;
    __syncthreads();
    for (int d = 1; d < FBT; d <<= 1) {
        int v = (t >= d) ? ls[t - d] : 0;
        __syncthreads();
        ls[t] += v;
        __syncthreads();
    }
    if (t <= nb) {
        int excl = ls[t] - ((t < nb) ? lh[t] : 0);
        if (t < nb) lcur[t] = excl;
        lps[t * nbb + blk] = excl;          // row nb = total
    }
    __syncthreads();
    // pass 2: place into stage
    idx = s0 + (t << 2);
    for (; idx + 3 < s1; idx += (FBT << 2)) {
        int4 d4 = *(const int4*)&dst[idx];
        int4 v4 = *(const int4*)&src[idx];
        int p0 = atomicAdd(&lcur[d4.x >> BSHIFT], 1);
        int p1 = atomicAdd(&lcur[d4.y >> BSHIFT], 1);
        int p2 = atomicAdd(&lcur[d4.z >> BSHIFT], 1);
        int p3 = atomicAdd(&lcur[d4.w >> BSHIFT], 1);
        stage[p0] = ((unsigned int)v4.x << BSHIFT) | (unsigned int)(d4.x & (BNODES - 1));
        stage[p1] = ((unsigned int)v4.y << BSHIFT) | (unsigned int)(d4.y & (BNODES - 1));
        stage[p2] = ((unsigned int)v4.z << BSHIFT) | (unsigned int)(d4.z & (BNODES - 1));
        stage[p3] = ((unsigned int)v4.w << BSHIFT) | (unsigned int)(d4.w & (BNODES - 1));
    }
    if (idx < s1) {
        int stop = min(idx + 4, s1);
        for (int e = idx; e < stop; ++e) {
            int d = dst[e];
            int pos = atomicAdd(&lcur[d >> BSHIFT], 1);
            stage[pos] = ((unsigned int)src[e] << BSHIFT) | (unsigned int)(d & (BNODES - 1));
        }
    }
    __syncthreads();
    // flush verbatim (coalesced)
    for (int k = t; k < tot; k += FBT) binned[s0 + k] = stage[k];
}

// ---------------------------------------------------------------------------
// local_sort: bucket b's edges live in cells binned[blk*per+st .. blk*per+en),
// st/en from lps rows b and b+1. Two passes over L2-hot cells:
//   pass1: per-node histogram -> scan -> cs/ce/dinv
//   pass2: placement col[b*PADCOL + pos] = src  (line-complete window)
// ---------------------------------------------------------------------------
__global__ __launch_bounds__(LST)
void local_sort_kernel(const unsigned int* __restrict__ binned,
                       const int* __restrict__ lps,
                       unsigned int* __restrict__ col, int* __restrict__ cs,
                       int* __restrict__ ce, float* __restrict__ dinv,
                       int n, int nb, int nbb, int per) {
    __shared__ int st[NBBMAX], en[NBBMAX];
    __shared__ int hist[BNODES], scn[BNODES], cur[BNODES];
    int b = blockIdx.x;
    int t = threadIdx.x;
    int colbase = b * PADCOL;

    for (int blk = t; blk < nbb; blk += LST) {
        st[blk] = lps[b * nbb + blk];
        en[blk] = lps[(b + 1) * nbb + blk];
    }
    if (t < BNODES) hist[t] = 0;
    __syncthreads();

    int g = t >> 4, l = t & 15;             // 32 groups of 16 lanes
    for (int blk = g; blk < nbb; blk += (LST >> 4)) {
        int base = blk * per;
        int e = en[blk];
        for (int k = st[blk] + l; k < e; k += 16)
            atomicAdd(&hist[binned[base + k] & (BNODES - 1)], 1);
    }
    __syncthreads();
    if (t < BNODES) scn[t] = hist[t];
    __syncthreads();
    for (int d = 1; d < BNODES; d <<= 1) {
        int v = (t < BNODES && t >= d) ? scn[t - d] : 0;
        __syncthreads();
        if (t < BNODES) scn[t] += v;
        __syncthreads();
    }
    if (t < BNODES) {
        int excl = scn[t] - hist[t];
        cur[t] = excl;
        int node = (b << BSHIFT) + t;
        if (node < n) {
            cs[node] = colbase + excl;
            ce[node] = colbase + excl + hist[t];
            dinv[node] = rsqrtf((float)hist[t] + 1.0f);
        }
    }
    __syncthreads();
    for (int blk = g; blk < nbb; blk += (LST >> 4)) {
        int base = blk * per;
        int e = en[blk];
        for (int k = st[blk] + l; k < e; k += 16) {
            unsigned int p = binned[base + k];
            int pos = atomicAdd(&cur[p & (BNODES - 1)], 1);
            col[colbase + pos] = p >> BSHIFT;
        }
    }
}

// ---------------------------------------------------------------------------
// hA[row,:] = fp16( dinv[row] * (x[row,:] @ W1) ), x staged in LDS coalesced
// ---------------------------------------------------------------------------
__global__ __launch_bounds__(256)
void gemm_kernel(const float* __restrict__ X, const float* __restrict__ W,
                 const float* __restrict__ dinv, __half* __restrict__ Yh, int n) {
    __shared__ float Wl[FIN * HDIM];       // 3456 B
    __shared__ float xl[GTILE * GPAD];     // 56320 B
    for (int t = threadIdx.x; t < FIN * HDIM; t += blockDim.x) Wl[t] = W[t];

    int base = blockIdx.x * GTILE;
    int nrows = min(GTILE, n - base);
    const float* xb = X + (size_t)base * FIN;
    int tot = nrows * FIN;
    for (int i4 = threadIdx.x; i4 < (tot >> 2); i4 += blockDim.x) {
        float4 v = ((const float4*)xb)[i4];
        int i = i4 << 2;
        int r = i / FIN;
        int c = i - r * FIN;
#pragma unroll
        for (int u = 0; u < 4; ++u) {
            int cc = c + u, rr = r;
            if (cc >= FIN) { cc -= FIN; ++rr; }
            xl[rr * GPAD + cc] = (&v.x)[u];
        }
    }
    for (int i = (tot & ~3) + threadIdx.x; i < tot; i += blockDim.x) {
        int r = i / FIN;
        xl[r * GPAD + (i - r * FIN)] = xb[i];
    }
    __syncthreads();

    int t = threadIdx.x;
    if (t < nrows) {
        int row = base + t;
        const float* xr = &xl[t * GPAD];
        float acc[HDIM];
#pragma unroll
        for (int j = 0; j < HDIM; ++j) acc[j] = 0.0f;
#pragma unroll
        for (int k = 0; k < FIN; ++k) {
            float xv = xr[k];
#pragma unroll
            for (int j = 0; j < HDIM; ++j)
                acc[j] = fmaf(xv, Wl[k * HDIM + j], acc[j]);
        }
        float di = dinv[row];
        __half2 hh[8];
#pragma unroll
        for (int j = 0; j < 8; ++j)
            hh[j] = __floats2half2_rn(di * acc[2 * j], di * acc[2 * j + 1]);
        uint4* yo = (uint4*)(Yh + ((size_t)row << 4));
        yo[0] = *(uint4*)&hh[0];
        yo[1] = *(uint4*)&hh[4];
    }
}

// ---------------------------------------------------------------------------
// Gather: 8 lanes per node (2 halves x 4 quarters). hs fp16, L2-resident.
// Each half sums alternating neighbors; halves combine via shfl_xor(4).
//   r = relu(dinv_i * (self + sum) + bias)
//   FUSE_W2: outh[i] = fp16(dinv_i * (r @ W2));  else out4[i] = r (f32)
// ---------------------------------------------------------------------------
__device__ __forceinline__ float4 ld_h4(const __half* __restrict__ hsh,
                                        unsigned int node, int q) {
    uint2 u = *(const uint2*)(hsh + ((size_t)node << 4) + (q << 2));
    __half2 a = *(__half2*)&u.x;
    __half2 b = *(__half2*)&u.y;
    float2 fa = __half22float2(a);
    float2 fb = __half22float2(b);
    return make_float4(fa.x, fa.y, fb.x, fb.y);
}

template <bool FUSE_W2>
__global__ void gather_kernel(const unsigned int* __restrict__ col,
                              const int* __restrict__ cs, const int* __restrict__ ce,
                              const __half* __restrict__ hsh, const float* __restrict__ dinv,
                              const float* __restrict__ bias, const float* __restrict__ W2,
                              __half* __restrict__ outh, float4* __restrict__ out4, int n) {
    __shared__ float4 W2l[HDIM * 4];   // W2l[jj*4+q] = W2[jj][4q..4q+3]
    if constexpr (FUSE_W2) {
        for (int t = threadIdx.x; t < HDIM * 4; t += blockDim.x)
            W2l[t] = ((const float4*)W2)[t];
        __syncthreads();
    }
    int idx = blockIdx.x * blockDim.x + threadIdx.x;
    int i = idx >> 3;
    int sub = idx & 7;
    int q = sub & 3;
    int h = sub >> 2;
    if (i >= n) return;
    int k0 = cs[i], k1 = ce[i];

    float4 acc = (h == 0) ? ld_h4(hsh, (unsigned int)i, q)   // self-loop on half 0
                          : make_float4(0.f, 0.f, 0.f, 0.f);
    int k = k0 + h;
    for (; k + 14 < k1; k += 16) {
        unsigned int s[8];
#pragma unroll
        for (int u = 0; u < 8; ++u) s[u] = col[k + 2 * u];
        float4 hv[8];
#pragma unroll
        for (int u = 0; u < 8; ++u) hv[u] = ld_h4(hsh, s[u], q);
#pragma unroll
        for (int u = 0; u < 8; ++u) {
            acc.x += hv[u].x; acc.y += hv[u].y; acc.z += hv[u].z; acc.w += hv[u].w;
        }
    }
    for (; k < k1; k += 2) {
        float4 hv = ld_h4(hsh, col[k], q);
        acc.x += hv.x; acc.y += hv.y; acc.z += hv.z; acc.w += hv.w;
    }
    // combine the two halves (partner = lane ^ 4)
    acc.x += __shfl_xor(acc.x, 4);
    acc.y += __shfl_xor(acc.y, 4);
    acc.z += __shfl_xor(acc.z, 4);
    acc.w += __shfl_xor(acc.w, 4);

    float di = dinv[i];
    float4 b4 = ((const float4*)bias)[q];
    float4 r;
    r.x = fmaxf(fmaf(di, acc.x, b4.x), 0.0f);
    r.y = fmaxf(fmaf(di, acc.y, b4.y), 0.0f);
    r.z = fmaxf(fmaf(di, acc.z, b4.z), 0.0f);
    r.w = fmaxf(fmaf(di, acc.w, b4.w), 0.0f);

    if constexpr (FUSE_W2) {
        int lane = threadIdx.x & 63;
        int base = lane & ~7;              // node's first lane (h=0, q=0)
        float4 o = make_float4(0.f, 0.f, 0.f, 0.f);
#pragma unroll
        for (int p = 0; p < 4; ++p) {      // lane base+p holds r for jj = 4p..4p+3
            float rx = __shfl(r.x, base + p, 64);
            float ry = __shfl(r.y, base + p, 64);
            float rz = __shfl(r.z, base + p, 64);
            float rw = __shfl(r.w, base + p, 64);
            float4 w0 = W2l[(p * 4 + 0) * 4 + q];
            float4 w1 = W2l[(p * 4 + 1) * 4 + q];
            float4 w2 = W2l[(p * 4 + 2) * 4 + q];
            float4 w3 = W2l[(p * 4 + 3) * 4 + q];
            o.x = fmaf(rx, w0.x, fmaf(ry, w1.x, fmaf(rz, w2.x, fmaf(rw, w3.x, o.x))));
            o.y = fmaf(rx, w0.y, fmaf(ry, w1.y, fmaf(rz, w2.y, fmaf(rw, w3.y, o.y))));
            o.z = fmaf(rx, w0.z, fmaf(ry, w1.z, fmaf(rz, w2.z, fmaf(rw, w3.z, o.z))));
            o.w = fmaf(rx, w0.w, fmaf(ry, w1.w, fmaf(rz, w2.w, fmaf(rw, w3.w, o.w))));
        }
        if (h == 0) {
            __half2 o01 = __floats2half2_rn(di * o.x, di * o.y);
            __half2 o23 = __floats2half2_rn(di * o.z, di * o.w);
            uint2 pk;
            pk.x = *(unsigned int*)&o01;
            pk.y = *(unsigned int*)&o23;
            *(uint2*)(outh + ((size_t)i << 4) + (q << 2)) = pk;
        }
    } else {
        if (h == 0) out4[(size_t)i * 4 + q] = r;
    }
}

extern "C" void kernel_launch(void* const* d_in, const int* in_sizes, int n_in,
                              void* d_out, int out_size, void* d_ws, size_t ws_size,
                              hipStream_t stream) {
    const float* x  = (const float*)d_in[0];   // [n, 54]
    const int*   ei = (const int*)d_in[1];     // [2, E]
    const float* W1 = (const float*)d_in[2];   // [54, 16]
    const float* b1 = (const float*)d_in[3];   // [16]
    const float* W2 = (const float*)d_in[4];   // [16, 16]
    const float* b2 = (const float*)d_in[5];   // [16]
    float* out = (float*)d_out;

    const int E = in_sizes[1] / 2;             // 3,200,000
    const int n = in_sizes[0] / FIN;           // 100,000
    const int* src = ei;
    const int* dst = ei + E;
    const int nb = (n + BNODES - 1) >> BSHIFT; // 782 buckets

    // fill blocks: per-block range fits the 50 KB stage
    int nbb = (E + 12499) / 12500;             // 256 for E = 3.2M
    if (nbb > NBBMAX) nbb = NBBMAX;
    int per = (((E + nbb - 1) / nbb) + 3) & ~3;  // 12500, multiple of 4, <= FPE

    char* w = (char*)d_ws;
    auto take = [&](size_t bytes) { char* p = w; w += (bytes + 255) & ~(size_t)255; return p; };
    float* dinv = (float*)take((size_t)n * 4);
    int*   lps  = (int*)take((size_t)(nb + 1) * nbb * 4);
    int*   cs   = (int*)take((size_t)n * 4);
    int*   ce   = (int*)take((size_t)n * 4);
    size_t binned_sz = (size_t)nbb * per * 4;
    size_t h_sz      = (size_t)n * HDIM * 2 * 2;      // hA + hB fp16
    char*  X    = take(binned_sz > h_sz ? binned_sz : h_sz);
    unsigned int* binned = (unsigned int*)X;
    __half* hA  = (__half*)X;                  // binned dead after build
    __half* hB  = (__half*)(X + (size_t)n * HDIM * 2);
    unsigned int* col = (unsigned int*)take((size_t)nb * PADCOL * 4);

    const int B = 256;

    // --- build: fill (self-scanned) -> local_sort (cells -> CSR + dinv) ---
    fill_binned_kernel<<<nbb, FBT, 0, stream>>>(src, dst, lps, binned, E, nb, nbb, per);
    local_sort_kernel<<<nb, LST, 0, stream>>>(binned, lps, col, cs, ce, dinv, n, nb, nbb, per);

    // --- layer 1 transform (pre-scaled by dinv, fp16 out); binned dead ---
    gemm_kernel<<<(n + GTILE - 1) / GTILE, B, 0, stream>>>(x, W1, dinv, hA, n);

    // --- layer 1 gather + relu + fused @W2 (pre-scaled, fp16) -> hB ---
    gather_kernel<true><<<(n * 8 + B - 1) / B, B, 0, stream>>>(
        col, cs, ce, hA, dinv, b1, W2, hB, nullptr, n);

    // --- layer 2 gather + bias + relu -> out (f32) ---
    gather_kernel<false><<<(n * 8 + B - 1) / B, B, 0, stream>>>(
        col, cs, ce, hB, dinv, b2, nullptr, nullptr, (float4*)out, n);
}

// Round 17
// 102.305 us; speedup vs baseline: 1.3793x; 1.0724x over previous
//
#include <hip/hip_runtime.h>
#include <hip/hip_fp16.h>

#define HDIM 16
#define FIN 54
#define BSHIFT 7                  // 128 nodes per bucket
#define BNODES (1 << BSHIFT)      // 128
#define NBMAXB 800                // LDS bucket arrays (nb = 782)
#define NBBMAX 512                // max fill blocks supported
#define FBT 1024                  // threads in fill blocks
#define LST 512                   // threads in local_sort blocks
#define FPE 12544                 // LDS stage entries in fill (50 KB)
#define PADCOL 6144               // col slots per bucket (mean 4092 + 32 sigma)
#define GPAD 55                   // padded x-row stride in LDS (55 mod 32 = 23)

// ---------------------------------------------------------------------------
// fill: self-contained binning. Block owns binned[blk*per .. blk*per+tot).
//   pass1: LDS bucket histogram (int4 loads)
//   scan : LDS exclusive scan -> local offsets; emit lps[b][blk] (b<=nb)
//   pass2: place packed (src<<7|dstLow) into LDS stage via cursors
//   flush: stage -> binned verbatim (stage is already bucket-sorted locally)
// ---------------------------------------------------------------------------
__global__ __launch_bounds__(FBT)
void fill_binned_kernel(const int* __restrict__ src, const int* __restrict__ dst,
                        int* __restrict__ lps, unsigned int* __restrict__ binned,
                        int E, int nb, int nbb, int per) {
    __shared__ unsigned int stage[FPE];     // 50 KB
    __shared__ int lh[NBMAXB], lcur[NBMAXB];
    __shared__ int ls[FBT];
    int blk = blockIdx.x;
    int s0 = blk * per;
    int s1 = min(E, s0 + per);
    int tot = s1 - s0;
    int t = threadIdx.x;

    for (int b = t; b < nb; b += FBT) lh[b] = 0;
    __syncthreads();
    // pass 1: histogram
    int idx = s0 + (t << 2);
    for (; idx + 3 < s1; idx += (FBT << 2)) {
        int4 d4 = *(const int4*)&dst[idx];
        atomicAdd(&lh[d4.x >> BSHIFT], 1);
        atomicAdd(&lh[d4.y >> BSHIFT], 1);
        atomicAdd(&lh[d4.z >> BSHIFT], 1);
        atomicAdd(&lh[d4.w >> BSHIFT], 1);
    }
    if (idx < s1) {
        int stop = min(idx + 4, s1);
        for (int e = idx; e < stop; ++e) atomicAdd(&lh[dst[e] >> BSHIFT], 1);
    }
    __syncthreads();
    // inclusive scan over buckets
    ls[t] = (t < nb) ? lh[t] : 0;
    __syncthreads();
    for (int d = 1; d < FBT; d <<= 1) {
        int v = (t >= d) ? ls[t - d] : 0;
        __syncthreads();
        ls[t] += v;
        __syncthreads();
    }
    if (t <= nb) {
        int excl = ls[t] - ((t < nb) ? lh[t] : 0);
        if (t < nb) lcur[t] = excl;
        lps[t * nbb + blk] = excl;          // row nb = total
    }
    __syncthreads();
    // pass 2: place into stage
    idx = s0 + (t << 2);
    for (; idx + 3 < s1; idx += (FBT << 2)) {
        int4 d4 = *(const int4*)&dst[idx];
        int4 v4 = *(const int4*)&src[idx];
        int p0 = atomicAdd(&lcur[d4.x >> BSHIFT], 1);
        int p1 = atomicAdd(&lcur[d4.y >> BSHIFT], 1);
        int p2 = atomicAdd(&lcur[d4.z >> BSHIFT], 1);
        int p3 = atomicAdd(&lcur[d4.w >> BSHIFT], 1);
        stage[p0] = ((unsigned int)v4.x << BSHIFT) | (unsigned int)(d4.x & (BNODES - 1));
        stage[p1] = ((unsigned int)v4.y << BSHIFT) | (unsigned int)(d4.y & (BNODES - 1));
        stage[p2] = ((unsigned int)v4.z << BSHIFT) | (unsigned int)(d4.z & (BNODES - 1));
        stage[p3] = ((unsigned int)v4.w << BSHIFT) | (unsigned int)(d4.w & (BNODES - 1));
    }
    if (idx < s1) {
        int stop = min(idx + 4, s1);
        for (int e = idx; e < stop; ++e) {
            int d = dst[e];
            int pos = atomicAdd(&lcur[d >> BSHIFT], 1);
            stage[pos] = ((unsigned int)src[e] << BSHIFT) | (unsigned int)(d & (BNODES - 1));
        }
    }
    __syncthreads();
    // flush verbatim (coalesced)
    for (int k = t; k < tot; k += FBT) binned[s0 + k] = stage[k];
}

// ---------------------------------------------------------------------------
// sort+gemm: bucket b's edges live in cells binned[blk*per+st .. blk*per+en).
//   stage x rows + W1 into LDS at entry (latency hides under sort phases)
//   pass1: per-node histogram -> scan -> cs/ce/dinv (di kept in register)
//   pass2: placement col[b*PADCOL + pos] = src  (line-complete window)
//   tail : thread t<nrows computes hA[row] = fp16(di * (x[row] @ W1))
// hA must NOT alias binned (read and write overlap in this kernel).
// ---------------------------------------------------------------------------
__global__ __launch_bounds__(LST)
void sort_gemm_kernel(const unsigned int* __restrict__ binned,
                      const int* __restrict__ lps,
                      const float* __restrict__ x, const float* __restrict__ W1,
                      unsigned int* __restrict__ col, int* __restrict__ cs,
                      int* __restrict__ ce, float* __restrict__ dinv,
                      __half* __restrict__ hA,
                      int n, int nb, int nbb, int per) {
    __shared__ int st[NBBMAX], en[NBBMAX];
    __shared__ int hist[BNODES], scn[BNODES], cur[BNODES];
    __shared__ float Wl[FIN * HDIM];        // 3456 B
    __shared__ float xl[BNODES * GPAD];     // 28160 B
    int b = blockIdx.x;
    int t = threadIdx.x;
    int colbase = b * PADCOL;
    int row0 = b << BSHIFT;
    int nrows = min(BNODES, n - row0);

    // --- stage x rows + W1 (completes before first barrier; latency hidden) ---
    const float* xb = x + (size_t)row0 * FIN;
    int tot = nrows * FIN;
    for (int i4 = t; i4 < (tot >> 2); i4 += LST) {
        float4 v = ((const float4*)xb)[i4];
        int i = i4 << 2;
        int r = i / FIN;
        int c = i - r * FIN;
#pragma unroll
        for (int u = 0; u < 4; ++u) {
            int cc = c + u, rr = r;
            if (cc >= FIN) { cc -= FIN; ++rr; }
            xl[rr * GPAD + cc] = (&v.x)[u];
        }
    }
    for (int i = (tot & ~3) + t; i < tot; i += LST) {
        int r = i / FIN;
        xl[r * GPAD + (i - r * FIN)] = xb[i];
    }
    for (int k = t; k < FIN * HDIM; k += LST) Wl[k] = W1[k];

    for (int blk = t; blk < nbb; blk += LST) {
        st[blk] = lps[b * nbb + blk];
        en[blk] = lps[(b + 1) * nbb + blk];
    }
    if (t < BNODES) hist[t] = 0;
    __syncthreads();

    // --- pass 1: per-node histogram over this bucket's cells ---
    int g = t >> 4, l = t & 15;             // 32 groups of 16 lanes
    for (int blk = g; blk < nbb; blk += (LST >> 4)) {
        int base = blk * per;
        int e = en[blk];
        for (int k = st[blk] + l; k < e; k += 16)
            atomicAdd(&hist[binned[base + k] & (BNODES - 1)], 1);
    }
    __syncthreads();
    if (t < BNODES) scn[t] = hist[t];
    __syncthreads();
    for (int d = 1; d < BNODES; d <<= 1) {
        int v = (t < BNODES && t >= d) ? scn[t - d] : 0;
        __syncthreads();
        if (t < BNODES) scn[t] += v;
        __syncthreads();
    }
    float di = 0.0f;
    if (t < BNODES) {
        int excl = scn[t] - hist[t];
        cur[t] = excl;
        int node = row0 + t;
        di = rsqrtf((float)hist[t] + 1.0f);
        if (node < n) {
            cs[node] = colbase + excl;
            ce[node] = colbase + excl + hist[t];
            dinv[node] = di;
        }
    }
    __syncthreads();
    // --- pass 2: placement ---
    for (int blk = g; blk < nbb; blk += (LST >> 4)) {
        int base = blk * per;
        int e = en[blk];
        for (int k = st[blk] + l; k < e; k += 16) {
            unsigned int p = binned[base + k];
            int pos = atomicAdd(&cur[p & (BNODES - 1)], 1);
            col[colbase + pos] = p >> BSHIFT;
        }
    }
    // --- gemm tail: deps (xl, Wl, di) are all pre-barrier / register ---
    if (t < nrows) {
        const float* xr = &xl[t * GPAD];
        float acc[HDIM];
#pragma unroll
        for (int j = 0; j < HDIM; ++j) acc[j] = 0.0f;
#pragma unroll
        for (int k = 0; k < FIN; ++k) {
            float xv = xr[k];
#pragma unroll
            for (int j = 0; j < HDIM; ++j)
                acc[j] = fmaf(xv, Wl[k * HDIM + j], acc[j]);
        }
        __half2 hh[8];
#pragma unroll
        for (int j = 0; j < 8; ++j)
            hh[j] = __floats2half2_rn(di * acc[2 * j], di * acc[2 * j + 1]);
        uint4* yo = (uint4*)(hA + ((size_t)(row0 + t) << 4));
        yo[0] = *(uint4*)&hh[0];
        yo[1] = *(uint4*)&hh[4];
    }
}

// ---------------------------------------------------------------------------
// Gather: 8 lanes per node (2 halves x 4 quarters). hs fp16, L2-resident.
// Each half sums alternating neighbors; halves combine via shfl_xor(4).
//   r = relu(dinv_i * (self + sum) + bias)
//   FUSE_W2: outh[i] = fp16(dinv_i * (r @ W2));  else out4[i] = r (f32)
// ---------------------------------------------------------------------------
__device__ __forceinline__ float4 ld_h4(const __half* __restrict__ hsh,
                                        unsigned int node, int q) {
    uint2 u = *(const uint2*)(hsh + ((size_t)node << 4) + (q << 2));
    __half2 a = *(__half2*)&u.x;
    __half2 b = *(__half2*)&u.y;
    float2 fa = __half22float2(a);
    float2 fb = __half22float2(b);
    return make_float4(fa.x, fa.y, fb.x, fb.y);
}

template <bool FUSE_W2>
__global__ void gather_kernel(const unsigned int* __restrict__ col,
                              const int* __restrict__ cs, const int* __restrict__ ce,
                              const __half* __restrict__ hsh, const float* __restrict__ dinv,
                              const float* __restrict__ bias, const float* __restrict__ W2,
                              __half* __restrict__ outh, float4* __restrict__ out4, int n) {
    __shared__ float4 W2l[HDIM * 4];   // W2l[jj*4+q] = W2[jj][4q..4q+3]
    if constexpr (FUSE_W2) {
        for (int t = threadIdx.x; t < HDIM * 4; t += blockDim.x)
            W2l[t] = ((const float4*)W2)[t];
        __syncthreads();
    }
    int idx = blockIdx.x * blockDim.x + threadIdx.x;
    int i = idx >> 3;
    int sub = idx & 7;
    int q = sub & 3;
    int h = sub >> 2;
    if (i >= n) return;
    int k0 = cs[i], k1 = ce[i];

    float4 acc = (h == 0) ? ld_h4(hsh, (unsigned int)i, q)   // self-loop on half 0
                          : make_float4(0.f, 0.f, 0.f, 0.f);
    int k = k0 + h;
    for (; k + 14 < k1; k += 16) {
        unsigned int s[8];
#pragma unroll
        for (int u = 0; u < 8; ++u) s[u] = col[k + 2 * u];
        float4 hv[8];
#pragma unroll
        for (int u = 0; u < 8; ++u) hv[u] = ld_h4(hsh, s[u], q);
#pragma unroll
        for (int u = 0; u < 8; ++u) {
            acc.x += hv[u].x; acc.y += hv[u].y; acc.z += hv[u].z; acc.w += hv[u].w;
        }
    }
    for (; k < k1; k += 2) {
        float4 hv = ld_h4(hsh, col[k], q);
        acc.x += hv.x; acc.y += hv.y; acc.z += hv.z; acc.w += hv.w;
    }
    // combine the two halves (partner = lane ^ 4)
    acc.x += __shfl_xor(acc.x, 4);
    acc.y += __shfl_xor(acc.y, 4);
    acc.z += __shfl_xor(acc.z, 4);
    acc.w += __shfl_xor(acc.w, 4);

    float di = dinv[i];
    float4 b4 = ((const float4*)bias)[q];
    float4 r;
    r.x = fmaxf(fmaf(di, acc.x, b4.x), 0.0f);
    r.y = fmaxf(fmaf(di, acc.y, b4.y), 0.0f);
    r.z = fmaxf(fmaf(di, acc.z, b4.z), 0.0f);
    r.w = fmaxf(fmaf(di, acc.w, b4.w), 0.0f);

    if constexpr (FUSE_W2) {
        int lane = threadIdx.x & 63;
        int base = lane & ~7;              // node's first lane (h=0, q=0)
        float4 o = make_float4(0.f, 0.f, 0.f, 0.f);
#pragma unroll
        for (int p = 0; p < 4; ++p) {      // lane base+p holds r for jj = 4p..4p+3
            float rx = __shfl(r.x, base + p, 64);
            float ry = __shfl(r.y, base + p, 64);
            float rz = __shfl(r.z, base + p, 64);
            float rw = __shfl(r.w, base + p, 64);
            float4 w0 = W2l[(p * 4 + 0) * 4 + q];
            float4 w1 = W2l[(p * 4 + 1) * 4 + q];
            float4 w2 = W2l[(p * 4 + 2) * 4 + q];
            float4 w3 = W2l[(p * 4 + 3) * 4 + q];
            o.x = fmaf(rx, w0.x, fmaf(ry, w1.x, fmaf(rz, w2.x, fmaf(rw, w3.x, o.x))));
            o.y = fmaf(rx, w0.y, fmaf(ry, w1.y, fmaf(rz, w2.y, fmaf(rw, w3.y, o.y))));
            o.z = fmaf(rx, w0.z, fmaf(ry, w1.z, fmaf(rz, w2.z, fmaf(rw, w3.z, o.z))));
            o.w = fmaf(rx, w0.w, fmaf(ry, w1.w, fmaf(rz, w2.w, fmaf(rw, w3.w, o.w))));
        }
        if (h == 0) {
            __half2 o01 = __floats2half2_rn(di * o.x, di * o.y);
            __half2 o23 = __floats2half2_rn(di * o.z, di * o.w);
            uint2 pk;
            pk.x = *(unsigned int*)&o01;
            pk.y = *(unsigned int*)&o23;
            *(uint2*)(outh + ((size_t)i << 4) + (q << 2)) = pk;
        }
    } else {
        if (h == 0) out4[(size_t)i * 4 + q] = r;
    }
}

extern "C" void kernel_launch(void* const* d_in, const int* in_sizes, int n_in,
                              void* d_out, int out_size, void* d_ws, size_t ws_size,
                              hipStream_t stream) {
    const float* x  = (const float*)d_in[0];   // [n, 54]
    const int*   ei = (const int*)d_in[1];     // [2, E]
    const float* W1 = (const float*)d_in[2];   // [54, 16]
    const float* b1 = (const float*)d_in[3];   // [16]
    const float* W2 = (const float*)d_in[4];   // [16, 16]
    const float* b2 = (const float*)d_in[5];   // [16]
    float* out = (float*)d_out;

    const int E = in_sizes[1] / 2;             // 3,200,000
    const int n = in_sizes[0] / FIN;           // 100,000
    const int* src = ei;
    const int* dst = ei + E;
    const int nb = (n + BNODES - 1) >> BSHIFT; // 782 buckets

    // fill blocks: per-block range fits the 50 KB stage
    int nbb = (E + 12499) / 12500;             // 256 for E = 3.2M
    if (nbb > NBBMAX) nbb = NBBMAX;
    int per = (((E + nbb - 1) / nbb) + 3) & ~3;  // 12500, multiple of 4, <= FPE

    char* w = (char*)d_ws;
    auto take = [&](size_t bytes) { char* p = w; w += (bytes + 255) & ~(size_t)255; return p; };
    float* dinv = (float*)take((size_t)n * 4);
    int*   lps  = (int*)take((size_t)(nb + 1) * nbb * 4);
    int*   cs   = (int*)take((size_t)n * 4);
    int*   ce   = (int*)take((size_t)n * 4);
    unsigned int* binned = (unsigned int*)take((size_t)nbb * per * 4);
    __half* hA  = (__half*)take((size_t)n * HDIM * 2);   // must NOT alias binned
    __half* hB  = (__half*)take((size_t)n * HDIM * 2);
    unsigned int* col = (unsigned int*)take((size_t)nb * PADCOL * 4);

    const int B = 256;

    // --- build: fill (self-scanned) -> sort+gemm (CSR + dinv + hA) ---
    fill_binned_kernel<<<nbb, FBT, 0, stream>>>(src, dst, lps, binned, E, nb, nbb, per);
    sort_gemm_kernel<<<nb, LST, 0, stream>>>(binned, lps, x, W1, col, cs, ce, dinv,
                                             hA, n, nb, nbb, per);

    // --- layer 1 gather + relu + fused @W2 (pre-scaled, fp16) -> hB ---
    gather_kernel<true><<<(n * 8 + B - 1) / B, B, 0, stream>>>(
        col, cs, ce, hA, dinv, b1, W2, hB, nullptr, n);

    // --- layer 2 gather + bias + relu -> out (f32) ---
    gather_kernel<false><<<(n * 8 + B - 1) / B, B, 0, stream>>>(
        col, cs, ce, hB, dinv, b2, nullptr, nullptr, (float4*)out, n);
}

// Round 18
// 93.549 us; speedup vs baseline: 1.5084x; 1.0936x over previous
//
#include <hip/hip_runtime.h>
#include <hip/hip_fp16.h>

#define HDIM 16
#define FIN 54
#define BSHIFT 7                  // 128 nodes per bucket
#define BNODES (1 << BSHIFT)      // 128
#define NBMAXB 800                // LDS bucket arrays (nb = 782)
#define NBBMAX 512                // max fill blocks supported
#define FBT 1024                  // threads in fill blocks
#define LST 512                   // threads in sort_gemm blocks
#define FPE 12544                 // LDS stage entries in fill (50 KB)
#define PADCOL 6144               // col slots per bucket (mean 4092 + 32 sigma)
#define GPAD 55                   // padded x-row stride in LDS (55 mod 32 = 23)

// ---------------------------------------------------------------------------
// fill: self-contained binning. Block owns binned[blk*per .. blk*per+tot).
//   pass1: LDS bucket histogram (int4 loads)
//   scan : LDS exclusive scan -> local offsets; emit lps[b][blk] (b<=nb)
//   pass2: place packed (src<<7|dstLow) into LDS stage via cursors
//   flush: stage -> binned verbatim (stage is already bucket-sorted locally)
// ---------------------------------------------------------------------------
__global__ __launch_bounds__(FBT)
void fill_binned_kernel(const int* __restrict__ src, const int* __restrict__ dst,
                        int* __restrict__ lps, unsigned int* __restrict__ binned,
                        int E, int nb, int nbb, int per) {
    __shared__ unsigned int stage[FPE];     // 50 KB
    __shared__ int lh[NBMAXB], lcur[NBMAXB];
    __shared__ int ls[FBT];
    int blk = blockIdx.x;
    int s0 = blk * per;
    int s1 = min(E, s0 + per);
    int tot = s1 - s0;
    int t = threadIdx.x;

    for (int b = t; b < nb; b += FBT) lh[b] = 0;
    __syncthreads();
    // pass 1: histogram
    int idx = s0 + (t << 2);
    for (; idx + 3 < s1; idx += (FBT << 2)) {
        int4 d4 = *(const int4*)&dst[idx];
        atomicAdd(&lh[d4.x >> BSHIFT], 1);
        atomicAdd(&lh[d4.y >> BSHIFT], 1);
        atomicAdd(&lh[d4.z >> BSHIFT], 1);
        atomicAdd(&lh[d4.w >> BSHIFT], 1);
    }
    if (idx < s1) {
        int stop = min(idx + 4, s1);
        for (int e = idx; e < stop; ++e) atomicAdd(&lh[dst[e] >> BSHIFT], 1);
    }
    __syncthreads();
    // inclusive scan over buckets
    ls[t] = (t < nb) ? lh[t] : 0;
    __syncthreads();
    for (int d = 1; d < FBT; d <<= 1) {
        int v = (t >= d) ? ls[t - d] : 0;
        __syncthreads();
        ls[t] += v;
        __syncthreads();
    }
    if (t <= nb) {
        int excl = ls[t] - ((t < nb) ? lh[t] : 0);
        if (t < nb) lcur[t] = excl;
        lps[t * nbb + blk] = excl;          // row nb = total
    }
    __syncthreads();
    // pass 2: place into stage
    idx = s0 + (t << 2);
    for (; idx + 3 < s1; idx += (FBT << 2)) {
        int4 d4 = *(const int4*)&dst[idx];
        int4 v4 = *(const int4*)&src[idx];
        int p0 = atomicAdd(&lcur[d4.x >> BSHIFT], 1);
        int p1 = atomicAdd(&lcur[d4.y >> BSHIFT], 1);
        int p2 = atomicAdd(&lcur[d4.z >> BSHIFT], 1);
        int p3 = atomicAdd(&lcur[d4.w >> BSHIFT], 1);
        stage[p0] = ((unsigned int)v4.x << BSHIFT) | (unsigned int)(d4.x & (BNODES - 1));
        stage[p1] = ((unsigned int)v4.y << BSHIFT) | (unsigned int)(d4.y & (BNODES - 1));
        stage[p2] = ((unsigned int)v4.z << BSHIFT) | (unsigned int)(d4.z & (BNODES - 1));
        stage[p3] = ((unsigned int)v4.w << BSHIFT) | (unsigned int)(d4.w & (BNODES - 1));
    }
    if (idx < s1) {
        int stop = min(idx + 4, s1);
        for (int e = idx; e < stop; ++e) {
            int d = dst[e];
            int pos = atomicAdd(&lcur[d >> BSHIFT], 1);
            stage[pos] = ((unsigned int)src[e] << BSHIFT) | (unsigned int)(d & (BNODES - 1));
        }
    }
    __syncthreads();
    // flush verbatim (coalesced)
    for (int k = t; k < tot; k += FBT) binned[s0 + k] = stage[k];
}

// ---------------------------------------------------------------------------
// sort+gemm: bucket b's edges live in cells binned[blk*per+st .. blk*per+en).
//   A: per-node histogram -> scan -> cs/ce/dinv (di kept in register)
//   B: placement into LDS stage (coalesced-flush pattern, R14 lesson)
//   C: flush stage -> col[colbase..] coalesced
//   D: reuse stage LDS as xl/Wl; stage x rows + W1; gemm tail -> hA fp16
// hA must NOT alias binned (read and write overlap in this kernel).
// ---------------------------------------------------------------------------
__global__ __launch_bounds__(LST)
void sort_gemm_kernel(const unsigned int* __restrict__ binned,
                      const int* __restrict__ lps,
                      const float* __restrict__ x, const float* __restrict__ W1,
                      unsigned int* __restrict__ col, int* __restrict__ cs,
                      int* __restrict__ ce, float* __restrict__ dinv,
                      __half* __restrict__ hA,
                      int n, int nb, int nbb, int per) {
    __shared__ int st[NBBMAX], en[NBBMAX];                  // 4 KB
    __shared__ int hist[BNODES], scn[BNODES], cur[BNODES];  // 1.5 KB
    __shared__ char ubuf[32768];                            // 32 KB shared phase buffer
    unsigned int* stage = (unsigned int*)ubuf;              // B/C: PADCOL u32 (24 KB)
    float* xl = (float*)ubuf;                               // D: 128*55 f32 (27.5 KB)
    float* Wl = (float*)(ubuf + BNODES * GPAD * 4);         // D: 54*16 f32 (3.4 KB)

    int b = blockIdx.x;
    int t = threadIdx.x;
    int colbase = b * PADCOL;
    int row0 = b << BSHIFT;
    int nrows = min(BNODES, n - row0);

    for (int blk = t; blk < nbb; blk += LST) {
        st[blk] = lps[b * nbb + blk];
        en[blk] = lps[(b + 1) * nbb + blk];
    }
    if (t < BNODES) hist[t] = 0;
    __syncthreads();

    // --- A: per-node histogram over this bucket's cells ---
    int g = t >> 4, l = t & 15;             // 32 groups of 16 lanes
    for (int blk = g; blk < nbb; blk += (LST >> 4)) {
        int base = blk * per;
        int e = en[blk];
        for (int k = st[blk] + l; k < e; k += 16)
            atomicAdd(&hist[binned[base + k] & (BNODES - 1)], 1);
    }
    __syncthreads();
    if (t < BNODES) scn[t] = hist[t];
    __syncthreads();
    for (int d = 1; d < BNODES; d <<= 1) {
        int v = (t < BNODES && t >= d) ? scn[t - d] : 0;
        __syncthreads();
        if (t < BNODES) scn[t] += v;
        __syncthreads();
    }
    float di = 0.0f;
    if (t < BNODES) {
        int excl = scn[t] - hist[t];
        cur[t] = excl;
        int node = row0 + t;
        di = rsqrtf((float)hist[t] + 1.0f);
        if (node < n) {
            cs[node] = colbase + excl;
            ce[node] = colbase + excl + hist[t];
            dinv[node] = di;
        }
    }
    __syncthreads();
    // --- B: placement into LDS stage ---
    for (int blk = g; blk < nbb; blk += (LST >> 4)) {
        int base = blk * per;
        int e = en[blk];
        for (int k = st[blk] + l; k < e; k += 16) {
            unsigned int p = binned[base + k];
            int pos = atomicAdd(&cur[p & (BNODES - 1)], 1);
            unsigned int sv = p >> BSHIFT;
            if (pos < PADCOL) stage[pos] = sv;
            else col[colbase + pos] = sv;   // statistically-never overflow
        }
    }
    __syncthreads();
    // --- C: coalesced flush ---
    int len = scn[BNODES - 1];
    if (len > PADCOL) len = PADCOL;
    for (int k = t; k < len; k += LST) col[colbase + k] = stage[k];
    __syncthreads();
    // --- D: reuse ubuf as xl/Wl; stage x + W1; gemm tail ---
    const float* xb = x + (size_t)row0 * FIN;
    int tot = nrows * FIN;
    for (int i4 = t; i4 < (tot >> 2); i4 += LST) {
        float4 v = ((const float4*)xb)[i4];
        int i = i4 << 2;
        int r = i / FIN;
        int c = i - r * FIN;
#pragma unroll
        for (int u = 0; u < 4; ++u) {
            int cc = c + u, rr = r;
            if (cc >= FIN) { cc -= FIN; ++rr; }
            xl[rr * GPAD + cc] = (&v.x)[u];
        }
    }
    for (int i = (tot & ~3) + t; i < tot; i += LST) {
        int r = i / FIN;
        xl[r * GPAD + (i - r * FIN)] = xb[i];
    }
    for (int k = t; k < FIN * HDIM; k += LST) Wl[k] = W1[k];
    __syncthreads();
    if (t < nrows) {
        const float* xr = &xl[t * GPAD];
        float acc[HDIM];
#pragma unroll
        for (int j = 0; j < HDIM; ++j) acc[j] = 0.0f;
#pragma unroll
        for (int k = 0; k < FIN; ++k) {
            float xv = xr[k];
#pragma unroll
            for (int j = 0; j < HDIM; ++j)
                acc[j] = fmaf(xv, Wl[k * HDIM + j], acc[j]);
        }
        __half2 hh[8];
#pragma unroll
        for (int j = 0; j < 8; ++j)
            hh[j] = __floats2half2_rn(di * acc[2 * j], di * acc[2 * j + 1]);
        uint4* yo = (uint4*)(hA + ((size_t)(row0 + t) << 4));
        yo[0] = *(uint4*)&hh[0];
        yo[1] = *(uint4*)&hh[4];
    }
}

// ---------------------------------------------------------------------------
// Gather: 8 lanes per node (2 halves x 4 quarters). hs fp16, L2-resident.
// Each half sums alternating neighbors; halves combine via shfl_xor(4).
//   r = relu(dinv_i * (self + sum) + bias)
//   FUSE_W2: outh[i] = fp16(dinv_i * (r @ W2));  else out4[i] = r (f32)
// ---------------------------------------------------------------------------
__device__ __forceinline__ float4 ld_h4(const __half* __restrict__ hsh,
                                        unsigned int node, int q) {
    uint2 u = *(const uint2*)(hsh + ((size_t)node << 4) + (q << 2));
    __half2 a = *(__half2*)&u.x;
    __half2 b = *(__half2*)&u.y;
    float2 fa = __half22float2(a);
    float2 fb = __half22float2(b);
    return make_float4(fa.x, fa.y, fb.x, fb.y);
}

template <bool FUSE_W2>
__global__ void gather_kernel(const unsigned int* __restrict__ col,
                              const int* __restrict__ cs, const int* __restrict__ ce,
                              const __half* __restrict__ hsh, const float* __restrict__ dinv,
                              const float* __restrict__ bias, const float* __restrict__ W2,
                              __half* __restrict__ outh, float4* __restrict__ out4, int n) {
    __shared__ float4 W2l[HDIM * 4];   // W2l[jj*4+q] = W2[jj][4q..4q+3]
    if constexpr (FUSE_W2) {
        for (int t = threadIdx.x; t < HDIM * 4; t += blockDim.x)
            W2l[t] = ((const float4*)W2)[t];
        __syncthreads();
    }
    int idx = blockIdx.x * blockDim.x + threadIdx.x;
    int i = idx >> 3;
    int sub = idx & 7;
    int q = sub & 3;
    int h = sub >> 2;
    if (i >= n) return;
    int k0 = cs[i], k1 = ce[i];

    float4 acc = (h == 0) ? ld_h4(hsh, (unsigned int)i, q)   // self-loop on half 0
                          : make_float4(0.f, 0.f, 0.f, 0.f);
    int k = k0 + h;
    for (; k + 14 < k1; k += 16) {
        unsigned int s[8];
#pragma unroll
        for (int u = 0; u < 8; ++u) s[u] = col[k + 2 * u];
        float4 hv[8];
#pragma unroll
        for (int u = 0; u < 8; ++u) hv[u] = ld_h4(hsh, s[u], q);
#pragma unroll
        for (int u = 0; u < 8; ++u) {
            acc.x += hv[u].x; acc.y += hv[u].y; acc.z += hv[u].z; acc.w += hv[u].w;
        }
    }
    for (; k < k1; k += 2) {
        float4 hv = ld_h4(hsh, col[k], q);
        acc.x += hv.x; acc.y += hv.y; acc.z += hv.z; acc.w += hv.w;
    }
    // combine the two halves (partner = lane ^ 4)
    acc.x += __shfl_xor(acc.x, 4);
    acc.y += __shfl_xor(acc.y, 4);
    acc.z += __shfl_xor(acc.z, 4);
    acc.w += __shfl_xor(acc.w, 4);

    float di = dinv[i];
    float4 b4 = ((const float4*)bias)[q];
    float4 r;
    r.x = fmaxf(fmaf(di, acc.x, b4.x), 0.0f);
    r.y = fmaxf(fmaf(di, acc.y, b4.y), 0.0f);
    r.z = fmaxf(fmaf(di, acc.z, b4.z), 0.0f);
    r.w = fmaxf(fmaf(di, acc.w, b4.w), 0.0f);

    if constexpr (FUSE_W2) {
        int lane = threadIdx.x & 63;
        int base = lane & ~7;              // node's first lane (h=0, q=0)
        float4 o = make_float4(0.f, 0.f, 0.f, 0.f);
#pragma unroll
        for (int p = 0; p < 4; ++p) {      // lane base+p holds r for jj = 4p..4p+3
            float rx = __shfl(r.x, base + p, 64);
            float ry = __shfl(r.y, base + p, 64);
            float rz = __shfl(r.z, base + p, 64);
            float rw = __shfl(r.w, base + p, 64);
            float4 w0 = W2l[(p * 4 + 0) * 4 + q];
            float4 w1 = W2l[(p * 4 + 1) * 4 + q];
            float4 w2 = W2l[(p * 4 + 2) * 4 + q];
            float4 w3 = W2l[(p * 4 + 3) * 4 + q];
            o.x = fmaf(rx, w0.x, fmaf(ry, w1.x, fmaf(rz, w2.x, fmaf(rw, w3.x, o.x))));
            o.y = fmaf(rx, w0.y, fmaf(ry, w1.y, fmaf(rz, w2.y, fmaf(rw, w3.y, o.y))));
            o.z = fmaf(rx, w0.z, fmaf(ry, w1.z, fmaf(rz, w2.z, fmaf(rw, w3.z, o.z))));
            o.w = fmaf(rx, w0.w, fmaf(ry, w1.w, fmaf(rz, w2.w, fmaf(rw, w3.w, o.w))));
        }
        if (h == 0) {
            __half2 o01 = __floats2half2_rn(di * o.x, di * o.y);
            __half2 o23 = __floats2half2_rn(di * o.z, di * o.w);
            uint2 pk;
            pk.x = *(unsigned int*)&o01;
            pk.y = *(unsigned int*)&o23;
            *(uint2*)(outh + ((size_t)i << 4) + (q << 2)) = pk;
        }
    } else {
        if (h == 0) out4[(size_t)i * 4 + q] = r;
    }
}

extern "C" void kernel_launch(void* const* d_in, const int* in_sizes, int n_in,
                              void* d_out, int out_size, void* d_ws, size_t ws_size,
                              hipStream_t stream) {
    const float* x  = (const float*)d_in[0];   // [n, 54]
    const int*   ei = (const int*)d_in[1];     // [2, E]
    const float* W1 = (const float*)d_in[2];   // [54, 16]
    const float* b1 = (const float*)d_in[3];   // [16]
    const float* W2 = (const float*)d_in[4];   // [16, 16]
    const float* b2 = (const float*)d_in[5];   // [16]
    float* out = (float*)d_out;

    const int E = in_sizes[1] / 2;             // 3,200,000
    const int n = in_sizes[0] / FIN;           // 100,000
    const int* src = ei;
    const int* dst = ei + E;
    const int nb = (n + BNODES - 1) >> BSHIFT; // 782 buckets

    // fill blocks: per-block range fits the 50 KB stage
    int nbb = (E + 12499) / 12500;             // 256 for E = 3.2M
    if (nbb > NBBMAX) nbb = NBBMAX;
    int per = (((E + nbb - 1) / nbb) + 3) & ~3;  // 12500, multiple of 4, <= FPE

    char* w = (char*)d_ws;
    auto take = [&](size_t bytes) { char* p = w; w += (bytes + 255) & ~(size_t)255; return p; };
    float* dinv = (float*)take((size_t)n * 4);
    int*   lps  = (int*)take((size_t)(nb + 1) * nbb * 4);
    int*   cs   = (int*)take((size_t)n * 4);
    int*   ce   = (int*)take((size_t)n * 4);
    unsigned int* binned = (unsigned int*)take((size_t)nbb * per * 4);
    __half* hA  = (__half*)take((size_t)n * HDIM * 2);   // must NOT alias binned
    __half* hB  = (__half*)take((size_t)n * HDIM * 2);
    unsigned int* col = (unsigned int*)take((size_t)nb * PADCOL * 4);

    const int B = 256;

    // --- build: fill (self-scanned) -> sort+gemm (CSR + dinv + hA) ---
    fill_binned_kernel<<<nbb, FBT, 0, stream>>>(src, dst, lps, binned, E, nb, nbb, per);
    sort_gemm_kernel<<<nb, LST, 0, stream>>>(binned, lps, x, W1, col, cs, ce, dinv,
                                             hA, n, nb, nbb, per);

    // --- layer 1 gather + relu + fused @W2 (pre-scaled, fp16) -> hB ---
    gather_kernel<true><<<(n * 8 + B - 1) / B, B, 0, stream>>>(
        col, cs, ce, hA, dinv, b1, W2, hB, nullptr, n);

    // --- layer 2 gather + bias + relu -> out (f32) ---
    gather_kernel<false><<<(n * 8 + B - 1) / B, B, 0, stream>>>(
        col, cs, ce, hB, dinv, b2, nullptr, nullptr, (float4*)out, n);
}